// Round 6
// baseline (351.511 us; speedup 1.0000x reference)
//
#include <hip/hip_runtime.h>
#include <hip/hip_bf16.h>

using short8 = __attribute__((ext_vector_type(8))) short;
using half8  = __attribute__((ext_vector_type(8))) _Float16;
using f32x4  = __attribute__((ext_vector_type(4))) float;

constexpr int Bdim = 16;
constexpr int Tdim = 1024;
constexpr int Sdim = 1024;
constexpr int Ddim = 1024;

__device__ __forceinline__ unsigned short f2hu(float x) {
  _Float16 h = (_Float16)x;
  return __builtin_bit_cast(unsigned short, h);
}
__device__ __forceinline__ float hu2f(unsigned short u) {
  return (float)__builtin_bit_cast(_Float16, u);
}

// ---------- split fp32 -> fp16 (hi, lo) ----------
__global__ void __launch_bounds__(256)
split2_kernel(const float* __restrict__ src, unsigned short* __restrict__ hi,
              unsigned short* __restrict__ lo, int n4) {
  int i = blockIdx.x * blockDim.x + threadIdx.x;
  int stride = gridDim.x * blockDim.x;
  for (; i < n4; i += stride) {
    float4 v = reinterpret_cast<const float4*>(src)[i];
    ushort4 h, l;
    h.x = f2hu(v.x); l.x = f2hu(v.x - hu2f(h.x));
    h.y = f2hu(v.y); l.y = f2hu(v.y - hu2f(h.y));
    h.z = f2hu(v.z); l.z = f2hu(v.z - hu2f(h.z));
    h.w = f2hu(v.w); l.w = f2hu(v.w - hu2f(h.w));
    reinterpret_cast<ushort4*>(hi)[i] = h;
    reinterpret_cast<ushort4*>(lo)[i] = l;
  }
}

// ---------- fp32 -> fp16 single ----------
__global__ void __launch_bounds__(256)
conv_kernel(const float* __restrict__ src, unsigned short* __restrict__ dst, int n4) {
  int i = blockIdx.x * blockDim.x + threadIdx.x;
  int stride = gridDim.x * blockDim.x;
  for (; i < n4; i += stride) {
    float4 v = reinterpret_cast<const float4*>(src)[i];
    ushort4 h;
    h.x = f2hu(v.x); h.y = f2hu(v.y); h.z = f2hu(v.z); h.w = f2hu(v.w);
    reinterpret_cast<ushort4*>(dst)[i] = h;
  }
}

// ---------- ctx [B,S,D] fp32 -> ctx16 [B,S,D] fp16 AND ctxT [B,D,S] fp16 ----------
__global__ void __launch_bounds__(256)
ctxprep_kernel(const float* __restrict__ ctx, unsigned short* __restrict__ ctx16,
               unsigned short* __restrict__ ctxT) {
  __shared__ float tile[64][65];
  int b = blockIdx.z;
  int d0 = blockIdx.x * 64, s0 = blockIdx.y * 64;
  const float* src = ctx + (size_t)b * Sdim * Ddim;
  unsigned short* dstS = ctx16 + (size_t)b * Sdim * Ddim;
  unsigned short* dstT = ctxT + (size_t)b * Ddim * Sdim;
  int tx = threadIdx.x & 15, ty = threadIdx.x >> 4;
  #pragma unroll
  for (int r = 0; r < 4; ++r) {
    int s = ty + r * 16;
    float4 v = reinterpret_cast<const float4*>(src + (size_t)(s0 + s) * Ddim + d0)[tx];
    ushort4 hs;
    hs.x = f2hu(v.x); hs.y = f2hu(v.y); hs.z = f2hu(v.z); hs.w = f2hu(v.w);
    reinterpret_cast<ushort4*>(dstS + (size_t)(s0 + s) * Ddim + d0)[tx] = hs;
    tile[s][tx * 4 + 0] = v.x; tile[s][tx * 4 + 1] = v.y;
    tile[s][tx * 4 + 2] = v.z; tile[s][tx * 4 + 3] = v.w;
  }
  __syncthreads();
  #pragma unroll
  for (int r = 0; r < 4; ++r) {
    int d = ty + r * 16;
    ushort4 o;
    o.x = f2hu(tile[tx * 4 + 0][d]);
    o.y = f2hu(tile[tx * 4 + 1][d]);
    o.z = f2hu(tile[tx * 4 + 2][d]);
    o.w = f2hu(tile[tx * 4 + 3][d]);
    reinterpret_cast<ushort4*>(dstT + (size_t)(d0 + d) * Sdim + s0)[tx] = o;
  }
}

// LDS frag read, 64B rows, XOR swizzle (0 bank conflicts r1-r5)
__device__ __forceinline__ short8 fragr(const unsigned short* t, int row, int g0) {
  int pg = g0 ^ ((row >> 1) & 3);
  return *reinterpret_cast<const short8*>(t + row * 32 + pg * 8);
}

#define MFMAH(d, x, y)                                                          \
  d = __builtin_amdgcn_mfma_f32_16x16x32_f16(__builtin_bit_cast(half8, (x)),    \
                                             __builtin_bit_cast(half8, (y)), (d), 0, 0, 0)

// ---------- 256x256-tile 8-wave GEMM, REG-STAGED double-buffer pipeline ----------
// C[m,n] = sum_k A[m,k]*B[n,k], K=1024 (B^T form), fp16 operands.
// TERMS=2: A split (Ah+Al), B single. TERMS=1: plain.
// MODE 0: out fp16 hi/lo at rr*1024+cc ; MODE 1: out f32 at (rr*16+bb)*1024+cc
template <int TERMS, int MODE>
__global__ void __launch_bounds__(512, 2)
gemmU(const unsigned short* __restrict__ Ah, const unsigned short* __restrict__ Al,
      const unsigned short* __restrict__ Bh,
      size_t aBatch, size_t bBatch, int mnShift,
      unsigned short* __restrict__ outHi, unsigned short* __restrict__ outLo,
      float* __restrict__ outF) {
  constexpr int OPS = TERMS + 1;
  constexpr int BUFSTRIDE = OPS * 8192;     // ushorts per buffer
  constexpr int NT = 32;                    // K-tiles, BK=32
  __shared__ __align__(16) unsigned short lds[2 * BUFSTRIDE];  // 96 / 64 KiB

  // XCD-chunked bijective swizzle (256 blocks)
  const int hw = blockIdx.x;
  const int L  = (hw & 7) * 32 + (hw >> 3);
  const int bb = L >> mnShift;
  const int r  = L & ((1 << mnShift) - 1);
  const int m0 = (r >> 2) * 256;
  const int n0 = (r & 3) * 256;

  const int tid  = threadIdx.x;
  const int lane = tid & 63;
  const int w    = tid >> 6;          // 8 waves: 2(M) x 4(N)
  const int wr   = (w >> 2) * 128;
  const int wc   = (w & 3) * 64;
  const int l15  = lane & 15;
  const int g0   = lane >> 4;

  // staging geometry: thread covers logical 16B granule (srow, gcol) of each
  // 128-row half; swizzle applied on the LDS WRITE (per-lane scatter ok)
  const int srow = tid >> 2;                               // 0..127
  const int gcol = tid & 3;
  const int woff = srow * 32 + ((gcol ^ ((srow >> 1) & 3)) * 8);  // ushort offset

  const unsigned short* gsrc[OPS * 2];
  {
    const size_t aOff = (size_t)bb * aBatch + (size_t)(m0 + srow) * 1024 + gcol * 8;
    const size_t bOff = (size_t)bb * bBatch + (size_t)(n0 + srow) * 1024 + gcol * 8;
    #pragma unroll
    for (int h = 0; h < 2; ++h) {
      gsrc[0 * 2 + h] = Ah + aOff + (size_t)h * (128 * 1024);
      if constexpr (TERMS == 2) gsrc[1 * 2 + h] = Al + aOff + (size_t)h * (128 * 1024);
      gsrc[(OPS - 1) * 2 + h] = Bh + bOff + (size_t)h * (128 * 1024);
    }
  }

  uint4 stg[OPS * 2];
  auto loadstg = [&](int kt) {
    #pragma unroll
    for (int i = 0; i < OPS * 2; ++i)
      stg[i] = *reinterpret_cast<const uint4*>(gsrc[i] + kt * 32);
  };
  auto writestg = [&](int buf) {
    unsigned short* wb = lds + buf * BUFSTRIDE + woff;
    #pragma unroll
    for (int i = 0; i < OPS * 2; ++i)
      *reinterpret_cast<uint4*>(wb + (i >> 1) * 8192 + (i & 1) * 4096) = stg[i];
  };

  f32x4 acc[8][4];
  const f32x4 vzero = {0.f, 0.f, 0.f, 0.f};
  #pragma unroll
  for (int f = 0; f < 8; ++f)
    #pragma unroll
    for (int j = 0; j < 4; ++j) acc[f][j] = vzero;

  short8 ah[4], al[4], b0[2], b1[2];

  // prologue: tile0 -> regs -> buf0; issue tile1 -> regs
  loadstg(0);
  writestg(0);
  loadstg(1);
  asm volatile("s_waitcnt lgkmcnt(0)" ::: "memory");
  __builtin_amdgcn_s_barrier();

  #pragma unroll 1
  for (int t = 0; t < NT; ++t) {
    const unsigned short* tb = lds + (t & 1) * BUFSTRIDE;
    const unsigned short* tA = tb;
    const unsigned short* tAl = tb + 8192;
    const unsigned short* tB = tb + (OPS - 1) * 8192;

    // q0: {f0-3 x j0-1}
    #pragma unroll
    for (int f = 0; f < 4; ++f) {
      ah[f] = fragr(tA, wr + f * 16 + l15, g0);
      if constexpr (TERMS == 2) al[f] = fragr(tAl, wr + f * 16 + l15, g0);
    }
    #pragma unroll
    for (int j = 0; j < 2; ++j) b0[j] = fragr(tB, wc + j * 16 + l15, g0);
    __builtin_amdgcn_s_setprio(1);
    #pragma unroll
    for (int f = 0; f < 4; ++f)
      #pragma unroll
      for (int j = 0; j < 2; ++j) {
        MFMAH(acc[f][j], ah[f], b0[j]);
        if constexpr (TERMS == 2) MFMAH(acc[f][j], al[f], b0[j]);
      }
    __builtin_amdgcn_s_setprio(0);

    // q1: {f0-3 x j2-3}
    #pragma unroll
    for (int j = 0; j < 2; ++j) b1[j] = fragr(tB, wc + (j + 2) * 16 + l15, g0);
    __builtin_amdgcn_s_setprio(1);
    #pragma unroll
    for (int f = 0; f < 4; ++f)
      #pragma unroll
      for (int j = 0; j < 2; ++j) {
        MFMAH(acc[f][j + 2], ah[f], b1[j]);
        if constexpr (TERMS == 2) MFMAH(acc[f][j + 2], al[f], b1[j]);
      }
    __builtin_amdgcn_s_setprio(0);

    // mid-tile staging: commit tile t+1 regs -> other buffer (vmcnt waits are
    // precise, inserted by compiler for the reg loads); issue tile t+2 loads
    if (t + 1 < NT) writestg((t + 1) & 1);
    if (t + 2 < NT) loadstg(t + 2);

    // q2: {f4-7 x j0-1}
    #pragma unroll
    for (int f = 0; f < 4; ++f) {
      ah[f] = fragr(tA, wr + 64 + f * 16 + l15, g0);
      if constexpr (TERMS == 2) al[f] = fragr(tAl, wr + 64 + f * 16 + l15, g0);
    }
    __builtin_amdgcn_s_setprio(1);
    #pragma unroll
    for (int f = 0; f < 4; ++f)
      #pragma unroll
      for (int j = 0; j < 2; ++j) {
        MFMAH(acc[4 + f][j], ah[f], b0[j]);
        if constexpr (TERMS == 2) MFMAH(acc[4 + f][j], al[f], b0[j]);
      }
    __builtin_amdgcn_s_setprio(0);

    // q3: {f4-7 x j2-3}
    __builtin_amdgcn_s_setprio(1);
    #pragma unroll
    for (int f = 0; f < 4; ++f)
      #pragma unroll
      for (int j = 0; j < 2; ++j) {
        MFMAH(acc[4 + f][j + 2], ah[f], b1[j]);
        if constexpr (TERMS == 2) MFMAH(acc[4 + f][j + 2], al[f], b1[j]);
      }
    __builtin_amdgcn_s_setprio(0);

    // commit ds_writes (and drained ds_reads) before releasing the buffers
    asm volatile("s_waitcnt lgkmcnt(0)" ::: "memory");
    __builtin_amdgcn_s_barrier();
  }

  // epilogue: C/D layout col=lane&15, row=(lane>>4)*4+q (m89/m91 verified)
  const int lr = (lane >> 4) * 4;
  const int lc = lane & 15;
  #pragma unroll
  for (int f = 0; f < 8; ++f)
    #pragma unroll
    for (int j = 0; j < 4; ++j)
      #pragma unroll
      for (int q = 0; q < 4; ++q) {
        int rr = m0 + wr + f * 16 + lr + q;
        int cc = n0 + wc + j * 16 + lc;
        float v = acc[f][j][q];
        if constexpr (MODE == 0) {
          unsigned short h = f2hu(v);
          unsigned short l = f2hu(v - hu2f(h));
          outHi[(size_t)rr * 1024 + cc] = h;
          outLo[(size_t)rr * 1024 + cc] = l;
        } else {
          outF[((size_t)rr * 16 + bb) * 1024 + cc] = v;
        }
      }
}

// ---------- in-place row softmax on [T,B,S] fp32 + fp16 copy to p[B,T,S] ----------
__global__ void __launch_bounds__(256)
softmax_kernel(float* __restrict__ av, unsigned short* __restrict__ p) {
  int row = blockIdx.x;           // row = t*16 + b
  int t = row >> 4, b = row & 15;
  float* a = av + (size_t)row * 1024;
  int tid = threadIdx.x, lane = tid & 63, wid = tid >> 6;
  float4 v = reinterpret_cast<float4*>(a)[tid];
  float mx = fmaxf(fmaxf(v.x, v.y), fmaxf(v.z, v.w));
  #pragma unroll
  for (int o = 1; o < 64; o <<= 1) mx = fmaxf(mx, __shfl_xor(mx, o));
  __shared__ float redM[4], redS[4];
  if (lane == 0) redM[wid] = mx;
  __syncthreads();
  mx = fmaxf(fmaxf(redM[0], redM[1]), fmaxf(redM[2], redM[3]));
  float e0 = __expf(v.x - mx), e1 = __expf(v.y - mx);
  float e2 = __expf(v.z - mx), e3 = __expf(v.w - mx);
  float s = (e0 + e1) + (e2 + e3);
  #pragma unroll
  for (int o = 1; o < 64; o <<= 1) s += __shfl_xor(s, o);
  if (lane == 0) redS[wid] = s;
  __syncthreads();
  s = (redS[0] + redS[1]) + (redS[2] + redS[3]);
  float inv = 1.0f / s;
  float4 o4;
  o4.x = e0 * inv; o4.y = e1 * inv; o4.z = e2 * inv; o4.w = e3 * inv;
  reinterpret_cast<float4*>(a)[tid] = o4;
  ushort4 pb;
  pb.x = f2hu(o4.x); pb.y = f2hu(o4.y); pb.z = f2hu(o4.z); pb.w = f2hu(o4.w);
  reinterpret_cast<ushort4*>(p + ((size_t)b * Tdim + t) * Sdim)[tid] = pb;
}

extern "C" void kernel_launch(void* const* d_in, const int* in_sizes, int n_in,
                              void* d_out, int out_size, void* d_ws, size_t ws_size,
                              hipStream_t stream) {
  const float* input = (const float*)d_in[0];  // [B,T,D]
  const float* ctx   = (const float*)d_in[1];  // [B,S,D]
  const float* Wt    = (const float*)d_in[2];  // [D,D]
  float* attn_out  = (float*)d_out;                               // [T,B,D]
  float* align_out = attn_out + (size_t)Tdim * Bdim * Ddim;       // [T,B,S]

  const size_t NE = (size_t)Bdim * Tdim * Ddim;  // 16M elems
  unsigned short* xh = (unsigned short*)d_ws;
  unsigned short* xl = xh + NE;
  unsigned short* Wh = xl + NE;
  unsigned short* hh = Wh + (size_t)Ddim * Ddim;
  unsigned short* hl = hh + NE;
  unsigned short* ctx16 = xh;   // after K1, x dead
  unsigned short* ctxT  = xl;
  unsigned short* p     = hh;   // after K2, h dead

  split2_kernel<<<2048, 256, 0, stream>>>(input, xh, xl, (int)(NE / 4));
  conv_kernel<<<512, 256, 0, stream>>>(Wt, Wh, (int)((size_t)Ddim * Ddim / 4));
  // K1: h = x @ W^T, A=x split, B=W single; out fp16 hi/lo
  gemmU<2, 0><<<256, 512, 0, stream>>>(xh, xl, Wh, 0, 0, 8, hh, hl, nullptr);
  // ctx16 [B,S,D] + ctxT [B,D,S] fp16 (into dead x regions)
  ctxprep_kernel<<<dim3(16, 16, Bdim), 256, 0, stream>>>(ctx, ctx16, ctxT);
  // K2: align = h @ ctx^T, A=h split, B=ctx single; out f32 [T,B,S]
  gemmU<2, 1><<<256, 512, 0, stream>>>(hh, hl, ctx16, (size_t)Tdim * Ddim,
                                       (size_t)Sdim * Ddim, 4, nullptr, nullptr, align_out);
  // softmax in-place + p fp16 [B,T,S]
  softmax_kernel<<<Bdim * Tdim, 256, 0, stream>>>(align_out, p);
  // K4: attn = p @ ctx, plain fp16; out f32 [T,B,D]
  gemmU<1, 1><<<256, 512, 0, stream>>>(p, nullptr, ctxT, (size_t)Tdim * Sdim,
                                       (size_t)Ddim * Sdim, 4, nullptr, nullptr, attn_out);
}

// Round 7
// 307.566 us; speedup vs baseline: 1.1429x; 1.1429x over previous
//
#include <hip/hip_runtime.h>
#include <hip/hip_bf16.h>

using short8 = __attribute__((ext_vector_type(8))) short;
using half8  = __attribute__((ext_vector_type(8))) _Float16;
using f32x4  = __attribute__((ext_vector_type(4))) float;

constexpr int Bdim = 16;
constexpr int Tdim = 1024;
constexpr int Sdim = 1024;
constexpr int Ddim = 1024;

__device__ __forceinline__ unsigned short f2hu(float x) {
  _Float16 h = (_Float16)x;
  return __builtin_bit_cast(unsigned short, h);
}
__device__ __forceinline__ float hu2f(unsigned short u) {
  return (float)__builtin_bit_cast(_Float16, u);
}

// ---------- split fp32 -> fp16 (hi, lo) ----------
__global__ void __launch_bounds__(256)
split2_kernel(const float* __restrict__ src, unsigned short* __restrict__ hi,
              unsigned short* __restrict__ lo, int n4) {
  int i = blockIdx.x * blockDim.x + threadIdx.x;
  int stride = gridDim.x * blockDim.x;
  for (; i < n4; i += stride) {
    float4 v = reinterpret_cast<const float4*>(src)[i];
    ushort4 h, l;
    h.x = f2hu(v.x); l.x = f2hu(v.x - hu2f(h.x));
    h.y = f2hu(v.y); l.y = f2hu(v.y - hu2f(h.y));
    h.z = f2hu(v.z); l.z = f2hu(v.z - hu2f(h.z));
    h.w = f2hu(v.w); l.w = f2hu(v.w - hu2f(h.w));
    reinterpret_cast<ushort4*>(hi)[i] = h;
    reinterpret_cast<ushort4*>(lo)[i] = l;
  }
}

// ---------- fp32 -> fp16 single ----------
__global__ void __launch_bounds__(256)
conv_kernel(const float* __restrict__ src, unsigned short* __restrict__ dst, int n4) {
  int i = blockIdx.x * blockDim.x + threadIdx.x;
  int stride = gridDim.x * blockDim.x;
  for (; i < n4; i += stride) {
    float4 v = reinterpret_cast<const float4*>(src)[i];
    ushort4 h;
    h.x = f2hu(v.x); h.y = f2hu(v.y); h.z = f2hu(v.z); h.w = f2hu(v.w);
    reinterpret_cast<ushort4*>(dst)[i] = h;
  }
}

// ---------- ctx [B,S,D] fp32 -> ctx16 [B,S,D] fp16 AND ctxT [B,D,S] fp16 ----------
__global__ void __launch_bounds__(256)
ctxprep_kernel(const float* __restrict__ ctx, unsigned short* __restrict__ ctx16,
               unsigned short* __restrict__ ctxT) {
  __shared__ float tile[64][65];
  int b = blockIdx.z;
  int d0 = blockIdx.x * 64, s0 = blockIdx.y * 64;
  const float* src = ctx + (size_t)b * Sdim * Ddim;
  unsigned short* dstS = ctx16 + (size_t)b * Sdim * Ddim;
  unsigned short* dstT = ctxT + (size_t)b * Ddim * Sdim;
  int tx = threadIdx.x & 15, ty = threadIdx.x >> 4;
  #pragma unroll
  for (int r = 0; r < 4; ++r) {
    int s = ty + r * 16;
    float4 v = reinterpret_cast<const float4*>(src + (size_t)(s0 + s) * Ddim + d0)[tx];
    ushort4 hs;
    hs.x = f2hu(v.x); hs.y = f2hu(v.y); hs.z = f2hu(v.z); hs.w = f2hu(v.w);
    reinterpret_cast<ushort4*>(dstS + (size_t)(s0 + s) * Ddim + d0)[tx] = hs;
    tile[s][tx * 4 + 0] = v.x; tile[s][tx * 4 + 1] = v.y;
    tile[s][tx * 4 + 2] = v.z; tile[s][tx * 4 + 3] = v.w;
  }
  __syncthreads();
  #pragma unroll
  for (int r = 0; r < 4; ++r) {
    int d = ty + r * 16;
    ushort4 o;
    o.x = f2hu(tile[tx * 4 + 0][d]);
    o.y = f2hu(tile[tx * 4 + 1][d]);
    o.z = f2hu(tile[tx * 4 + 2][d]);
    o.w = f2hu(tile[tx * 4 + 3][d]);
    reinterpret_cast<ushort4*>(dstT + (size_t)(d0 + d) * Sdim + s0)[tx] = o;
  }
}

#define MFMAH(d, x, y)                                                          \
  d = __builtin_amdgcn_mfma_f32_16x16x32_f16(__builtin_bit_cast(half8, (x)),    \
                                             __builtin_bit_cast(half8, (y)), (d), 0, 0, 0)

// ---------- 256x256-tile 8-wave GEMM, BK=64, A-in-LDS(dbuf DMA), B-in-regs ----------
// C[m,n] = sum_k A[m,k]*B[n,k], K=1024 (B^T form), fp16.
// TERMS=2: A = Ah+Al (split), 2 MFMA per (f,j,kk). TERMS=1: plain.
// MODE 0: out fp16 hi/lo at rr*1024+cc ; MODE 1: out f32 at (rr*16+bb)*1024+cc
template <int TERMS, int MODE>
__global__ void __launch_bounds__(512, 2)
gemmV(const unsigned short* __restrict__ Ah, const unsigned short* __restrict__ Al,
      const unsigned short* __restrict__ Bg,
      size_t aBatch, size_t bBatch, int mnShift,
      unsigned short* __restrict__ outHi, unsigned short* __restrict__ outLo,
      float* __restrict__ outF) {
  constexpr int OPS = TERMS;               // A operands in LDS
  constexpr int NT  = 16;                  // K-tiles, BK=64
  __shared__ __align__(16) unsigned short lds[2 * OPS * 16384];  // 128 / 64 KiB

  // XCD-chunked bijective swizzle (256 blocks)
  const int hw = blockIdx.x;
  const int L  = (hw & 7) * 32 + (hw >> 3);
  const int bb = L >> mnShift;
  const int r  = L & ((1 << mnShift) - 1);
  const int m0 = (r >> 2) * 256;
  const int n0 = (r & 3) * 256;

  const int tid  = threadIdx.x;
  const int lane = tid & 63;
  const int w    = tid >> 6;          // 8 waves: 2(M) x 4(N)
  const int wr   = (w >> 2) * 128;
  const int wc   = (w & 3) * 64;
  const int l15  = lane & 15;
  const int g0   = lane >> 4;
  const int r7   = l15 & 7;

  // ---- A staging: 128B rows, 8 granules; XOR swizzle pg = g ^ (row&7).
  // Linear LDS dest (DMA requirement), pre-swizzled global source column.
  const int srow8 = tid >> 3;                        // 0..63
  const int sg    = tid & 7;
  const int rs    = srow8 & 7;
  const unsigned short* spA[OPS];
  {
    const size_t aOff = (size_t)bb * aBatch + (size_t)(m0 + srow8) * 1024 + ((sg ^ rs) * 8);
    spA[0] = Ah + aOff;
    if constexpr (TERMS == 2) spA[1] = Al + aOff;
  }
  auto stage_A = [&](int buf, int kt) {
    #pragma unroll
    for (int op = 0; op < OPS; ++op)
      #pragma unroll
      for (int i = 0; i < 4; ++i) {
        const unsigned short* g = spA[op] + (size_t)i * (64 * 1024) + kt * 64;
        unsigned short* l = lds + buf * (OPS * 16384) + op * 16384 +
                            (srow8 + i * 64) * 64 + sg * 8;
        __builtin_amdgcn_global_load_lds((const __attribute__((address_space(1))) void*)g,
                                         (__attribute__((address_space(3))) void*)l, 16, 0, 0);
      }
  };

  // ---- B fragments straight from global (L2-resident) into regs, dbuf ----
  const unsigned short* pB = Bg + (size_t)bb * bBatch + (size_t)(n0 + wc + l15) * 1024 + g0 * 8;
  auto bload = [&](uint4 (&br)[4][2], int kt) {
    #pragma unroll
    for (int j = 0; j < 4; ++j)
      #pragma unroll
      for (int kk = 0; kk < 2; ++kk)
        br[j][kk] = *reinterpret_cast<const uint4*>(pB + (size_t)j * 16 * 1024 + kt * 64 + kk * 32);
  };

  f32x4 acc[8][4];
  const f32x4 vzero = {0.f, 0.f, 0.f, 0.f};
  #pragma unroll
  for (int f = 0; f < 8; ++f)
    #pragma unroll
    for (int j = 0; j < 4; ++j) acc[f][j] = vzero;

  uint4 b0[4][2], b1[4][2];

  // prologue: A(0) first (oldest -> drained by the counted vmcnt), then B(0)
  stage_A(0, 0);
  bload(b0, 0);

  // one tile: 2 barriers, counted vmcnt leaves {A(t+1), B(t)} in flight
  auto tilebody = [&](int t, uint4 (&bc)[4][2], uint4 (&bn)[4][2]) {
    const int tn = (t + 1 < NT) ? t + 1 : NT - 1;
    stage_A((t + 1) & 1, tn);
    if constexpr (TERMS == 2) asm volatile("s_waitcnt vmcnt(16)" ::: "memory");
    else                      asm volatile("s_waitcnt vmcnt(12)" ::: "memory");
    __builtin_amdgcn_s_barrier();
    asm volatile("" ::: "memory");
    const unsigned short* tb = lds + (t & 1) * (OPS * 16384);

    #pragma unroll
    for (int fp = 0; fp < 4; ++fp) {
      if (fp == 2) bload(bn, tn);      // prefetch next tile's B mid-tile
      short8 ah[2][2], al[2][2];
      #pragma unroll
      for (int f2 = 0; f2 < 2; ++f2) {
        const int row = wr + (fp * 2 + f2) * 16 + l15;
        #pragma unroll
        for (int kk = 0; kk < 2; ++kk) {
          const int pg = (kk * 4 + g0) ^ r7;
          ah[f2][kk] = *reinterpret_cast<const short8*>(tb + row * 64 + pg * 8);
          if constexpr (TERMS == 2)
            al[f2][kk] = *reinterpret_cast<const short8*>(tb + 16384 + row * 64 + pg * 8);
        }
      }
      __builtin_amdgcn_s_setprio(1);
      #pragma unroll
      for (int f2 = 0; f2 < 2; ++f2)
        #pragma unroll
        for (int j = 0; j < 4; ++j)
          #pragma unroll
          for (int kk = 0; kk < 2; ++kk) {
            MFMAH(acc[fp * 2 + f2][j], ah[f2][kk], bc[j][kk]);
            if constexpr (TERMS == 2) MFMAH(acc[fp * 2 + f2][j], al[f2][kk], bc[j][kk]);
          }
      __builtin_amdgcn_s_setprio(0);
    }
    // all ds_reads of this buffer retired before anyone DMAs over it next tile
    asm volatile("s_waitcnt lgkmcnt(0)" ::: "memory");
    __builtin_amdgcn_sched_barrier(0);
    __builtin_amdgcn_s_barrier();
  };

  #pragma unroll 1
  for (int it = 0; it < NT / 2; ++it) {
    tilebody(2 * it,     b0, b1);
    tilebody(2 * it + 1, b1, b0);
  }

  // epilogue: C/D layout col=lane&15, row=(lane>>4)*4+q (m89/m91 verified)
  const int lr = (lane >> 4) * 4;
  const int lc = lane & 15;
  #pragma unroll
  for (int f = 0; f < 8; ++f)
    #pragma unroll
    for (int j = 0; j < 4; ++j)
      #pragma unroll
      for (int q = 0; q < 4; ++q) {
        int rr = m0 + wr + f * 16 + lr + q;
        int cc = n0 + wc + j * 16 + lc;
        float v = acc[f][j][q];
        if constexpr (MODE == 0) {
          unsigned short h = f2hu(v);
          unsigned short l = f2hu(v - hu2f(h));
          outHi[(size_t)rr * 1024 + cc] = h;
          outLo[(size_t)rr * 1024 + cc] = l;
        } else {
          outF[((size_t)rr * 16 + bb) * 1024 + cc] = v;
        }
      }
}

// ---------- in-place row softmax on [T,B,S] fp32 + fp16 copy to p[B,T,S] ----------
__global__ void __launch_bounds__(256)
softmax_kernel(float* __restrict__ av, unsigned short* __restrict__ p) {
  int row = blockIdx.x;           // row = t*16 + b
  int t = row >> 4, b = row & 15;
  float* a = av + (size_t)row * 1024;
  int tid = threadIdx.x, lane = tid & 63, wid = tid >> 6;
  float4 v = reinterpret_cast<float4*>(a)[tid];
  float mx = fmaxf(fmaxf(v.x, v.y), fmaxf(v.z, v.w));
  #pragma unroll
  for (int o = 1; o < 64; o <<= 1) mx = fmaxf(mx, __shfl_xor(mx, o));
  __shared__ float redM[4], redS[4];
  if (lane == 0) redM[wid] = mx;
  __syncthreads();
  mx = fmaxf(fmaxf(redM[0], redM[1]), fmaxf(redM[2], redM[3]));
  float e0 = __expf(v.x - mx), e1 = __expf(v.y - mx);
  float e2 = __expf(v.z - mx), e3 = __expf(v.w - mx);
  float s = (e0 + e1) + (e2 + e3);
  #pragma unroll
  for (int o = 1; o < 64; o <<= 1) s += __shfl_xor(s, o);
  if (lane == 0) redS[wid] = s;
  __syncthreads();
  s = (redS[0] + redS[1]) + (redS[2] + redS[3]);
  float inv = 1.0f / s;
  float4 o4;
  o4.x = e0 * inv; o4.y = e1 * inv; o4.z = e2 * inv; o4.w = e3 * inv;
  reinterpret_cast<float4*>(a)[tid] = o4;
  ushort4 pb;
  pb.x = f2hu(o4.x); pb.y = f2hu(o4.y); pb.z = f2hu(o4.z); pb.w = f2hu(o4.w);
  reinterpret_cast<ushort4*>(p + ((size_t)b * Tdim + t) * Sdim)[tid] = pb;
}

extern "C" void kernel_launch(void* const* d_in, const int* in_sizes, int n_in,
                              void* d_out, int out_size, void* d_ws, size_t ws_size,
                              hipStream_t stream) {
  const float* input = (const float*)d_in[0];  // [B,T,D]
  const float* ctx   = (const float*)d_in[1];  // [B,S,D]
  const float* Wt    = (const float*)d_in[2];  // [D,D]
  float* attn_out  = (float*)d_out;                               // [T,B,D]
  float* align_out = attn_out + (size_t)Tdim * Bdim * Ddim;       // [T,B,S]

  const size_t NE = (size_t)Bdim * Tdim * Ddim;  // 16M elems
  unsigned short* xh = (unsigned short*)d_ws;
  unsigned short* xl = xh + NE;
  unsigned short* Wh = xl + NE;
  unsigned short* hh = Wh + (size_t)Ddim * Ddim;
  unsigned short* hl = hh + NE;
  unsigned short* ctx16 = xh;   // after K1, x dead
  unsigned short* ctxT  = xl;
  unsigned short* p     = hh;   // after K2, h dead

  split2_kernel<<<2048, 256, 0, stream>>>(input, xh, xl, (int)(NE / 4));
  conv_kernel<<<512, 256, 0, stream>>>(Wt, Wh, (int)((size_t)Ddim * Ddim / 4));
  // K1: h = x @ W^T, A=x split (LDS), B=W (regs from L2); out fp16 hi/lo
  gemmV<2, 0><<<256, 512, 0, stream>>>(xh, xl, Wh, 0, 0, 8, hh, hl, nullptr);
  // ctx16 [B,S,D] + ctxT [B,D,S] fp16 (into dead x regions)
  ctxprep_kernel<<<dim3(16, 16, Bdim), 256, 0, stream>>>(ctx, ctx16, ctxT);
  // K2: align = h @ ctx^T, A=h split, B=ctx16; out f32 [T,B,S]
  gemmV<2, 1><<<256, 512, 0, stream>>>(hh, hl, ctx16, (size_t)Tdim * Ddim,
                                       (size_t)Sdim * Ddim, 4, nullptr, nullptr, align_out);
  // softmax in-place + p fp16 [B,T,S]
  softmax_kernel<<<Bdim * Tdim, 256, 0, stream>>>(align_out, p);
  // K4: attn = p @ ctx, plain fp16, A=p, B=ctxT; out f32 [T,B,D]
  gemmV<1, 1><<<256, 512, 0, stream>>>(p, nullptr, ctxT, (size_t)Tdim * Sdim,
                                       (size_t)Ddim * Sdim, 4, nullptr, nullptr, attn_out);
}

// Round 8
// 220.535 us; speedup vs baseline: 1.5939x; 1.3946x over previous
//
#include <hip/hip_runtime.h>
#include <hip/hip_bf16.h>

using short8 = __attribute__((ext_vector_type(8))) short;
using half8  = __attribute__((ext_vector_type(8))) _Float16;
using f32x4  = __attribute__((ext_vector_type(4))) float;

constexpr int Bdim = 16;
constexpr int Tdim = 1024;
constexpr int Sdim = 1024;
constexpr int Ddim = 1024;

__device__ __forceinline__ unsigned short f2hu(float x) {
  _Float16 h = (_Float16)x;
  return __builtin_bit_cast(unsigned short, h);
}
__device__ __forceinline__ float hu2f(unsigned short u) {
  return (float)__builtin_bit_cast(_Float16, u);
}

// ---------- fp32 -> fp16 single ----------
__global__ void __launch_bounds__(256)
conv_kernel(const float* __restrict__ src, unsigned short* __restrict__ dst, int n4) {
  int i = blockIdx.x * blockDim.x + threadIdx.x;
  int stride = gridDim.x * blockDim.x;
  for (; i < n4; i += stride) {
    float4 v = reinterpret_cast<const float4*>(src)[i];
    ushort4 h;
    h.x = f2hu(v.x); h.y = f2hu(v.y); h.z = f2hu(v.z); h.w = f2hu(v.w);
    reinterpret_cast<ushort4*>(dst)[i] = h;
  }
}

// ---------- ctx [B,S,D] fp32 -> ctx16 [B,S,D] fp16 AND ctxT [B,D,S] fp16 ----------
__global__ void __launch_bounds__(256)
ctxprep_kernel(const float* __restrict__ ctx, unsigned short* __restrict__ ctx16,
               unsigned short* __restrict__ ctxT) {
  __shared__ float tile[64][65];
  int b = blockIdx.z;
  int d0 = blockIdx.x * 64, s0 = blockIdx.y * 64;
  const float* src = ctx + (size_t)b * Sdim * Ddim;
  unsigned short* dstS = ctx16 + (size_t)b * Sdim * Ddim;
  unsigned short* dstT = ctxT + (size_t)b * Ddim * Sdim;
  int tx = threadIdx.x & 15, ty = threadIdx.x >> 4;
  #pragma unroll
  for (int r = 0; r < 4; ++r) {
    int s = ty + r * 16;
    float4 v = reinterpret_cast<const float4*>(src + (size_t)(s0 + s) * Ddim + d0)[tx];
    ushort4 hs;
    hs.x = f2hu(v.x); hs.y = f2hu(v.y); hs.z = f2hu(v.z); hs.w = f2hu(v.w);
    reinterpret_cast<ushort4*>(dstS + (size_t)(s0 + s) * Ddim + d0)[tx] = hs;
    tile[s][tx * 4 + 0] = v.x; tile[s][tx * 4 + 1] = v.y;
    tile[s][tx * 4 + 2] = v.z; tile[s][tx * 4 + 3] = v.w;
  }
  __syncthreads();
  #pragma unroll
  for (int r = 0; r < 4; ++r) {
    int d = ty + r * 16;
    ushort4 o;
    o.x = f2hu(tile[tx * 4 + 0][d]);
    o.y = f2hu(tile[tx * 4 + 1][d]);
    o.z = f2hu(tile[tx * 4 + 2][d]);
    o.w = f2hu(tile[tx * 4 + 3][d]);
    reinterpret_cast<ushort4*>(dstT + (size_t)(d0 + d) * Sdim + s0)[tx] = o;
  }
}

// LDS frag read, 64B rows, XOR swizzle (0 conflicts r1-r5)
__device__ __forceinline__ short8 fragr(const unsigned short* t, int row, int g0) {
  int pg = g0 ^ ((row >> 1) & 3);
  return *reinterpret_cast<const short8*>(t + row * 32 + pg * 8);
}

#define MFMAH(d, x, y)                                                          \
  d = __builtin_amdgcn_mfma_f32_16x16x32_f16(__builtin_bit_cast(half8, (x)),    \
                                             __builtin_bit_cast(half8, (y)), (d), 0, 0, 0)

#define GLOADLDS(g, l)                                                          \
  __builtin_amdgcn_global_load_lds((const __attribute__((address_space(1))) void*)(g), \
                                   (__attribute__((address_space(3))) void*)(l), 16, 0, 0)

// ---------- PLAIN fp16 GEMM: 256x256 tile, BK=64, dbuf 128 KiB, NT=16 ----------
// C[m,n] = sum_k A[m,k]*B[n,k], K=1024 (B^T form).
// MODE 0: out fp16 hi/lo at rr*1024+cc ; MODE 1: out f32 at (rr*16+bb)*1024+cc
template <int MODE>
__global__ void __launch_bounds__(512, 2)
gemmP(const unsigned short* __restrict__ Ag, const unsigned short* __restrict__ Bg,
      size_t aBatch, size_t bBatch, int mnShift,
      unsigned short* __restrict__ outHi, unsigned short* __restrict__ outLo,
      float* __restrict__ outF) {
  constexpr int NT = 16;
  __shared__ __align__(16) unsigned short lds[2 * 2 * 16384];  // [buf][op][256*64]

  const int hw = blockIdx.x;
  const int L  = (hw & 7) * 32 + (hw >> 3);
  const int bb = L >> mnShift;
  const int r  = L & ((1 << mnShift) - 1);
  const int m0 = (r >> 2) * 256;
  const int n0 = (r & 3) * 256;

  const int tid  = threadIdx.x;
  const int lane = tid & 63;
  const int w    = tid >> 6;          // 8 waves: 2(M) x 4(N)
  const int wr   = (w >> 2) * 128;
  const int wc   = (w & 3) * 64;
  const int l15  = lane & 15;
  const int g0   = lane >> 4;
  const int r7   = l15 & 7;

  // staging: 128B rows (64 fp16), 8 granules; swizzle pg = g ^ (row&7);
  // linear LDS dest + pre-swizzled global source col (proven in r7, 0 conflicts)
  const int srow8 = tid >> 3;        // 0..63
  const int sg    = tid & 7;
  const int rs    = srow8 & 7;
  const unsigned short* spA = Ag + (size_t)bb * aBatch + (size_t)(m0 + srow8) * 1024 + ((sg ^ rs) * 8);
  const unsigned short* spB = Bg + (size_t)bb * bBatch + (size_t)(n0 + srow8) * 1024 + ((sg ^ rs) * 8);

  auto stage = [&](int buf, int kt) {
    #pragma unroll
    for (int i = 0; i < 4; ++i) {
      unsigned short* lb = lds + buf * 32768 + (srow8 + i * 64) * 64 + sg * 8;
      GLOADLDS(spA + (size_t)i * (64 * 1024) + kt * 64, lb);
      GLOADLDS(spB + (size_t)i * (64 * 1024) + kt * 64, lb + 16384);
    }
  };

  f32x4 acc[8][4];
  const f32x4 vzero = {0.f, 0.f, 0.f, 0.f};
  #pragma unroll
  for (int f = 0; f < 8; ++f)
    #pragma unroll
    for (int j = 0; j < 4; ++j) acc[f][j] = vzero;

  stage(0, 0);

  #pragma unroll 1
  for (int t = 0; t < NT; ++t) {
    // stage next tile (benign re-stage at tail keeps vmcnt topology uniform)
    stage((t + 1) & 1, (t + 1 < NT) ? (t + 1) : (NT - 1));
    // wait tile t's 8 loads (issued one round ago); leave t+1's 8 in flight
    asm volatile("s_waitcnt vmcnt(8)" ::: "memory");
    __builtin_amdgcn_s_barrier();
    asm volatile("" ::: "memory");
    const unsigned short* tb = lds + (t & 1) * 32768;
    const unsigned short* tB = tb + 16384;

    // B frags (8): rows wc+j*16+l15, kk granule (kk*4+g0)^r7
    short8 bf[4][2];
    #pragma unroll
    for (int j = 0; j < 4; ++j)
      #pragma unroll
      for (int kk = 0; kk < 2; ++kk) {
        const int row = wc + j * 16 + l15;
        bf[j][kk] = *reinterpret_cast<const short8*>(tB + row * 64 + ((kk * 4 + g0) ^ r7) * 8);
      }
    // A in 4 chunks of 2 M-frags
    #pragma unroll
    for (int fp = 0; fp < 4; ++fp) {
      short8 af[2][2];
      #pragma unroll
      for (int f2 = 0; f2 < 2; ++f2) {
        const int row = wr + (fp * 2 + f2) * 16 + l15;
        #pragma unroll
        for (int kk = 0; kk < 2; ++kk)
          af[f2][kk] = *reinterpret_cast<const short8*>(tb + row * 64 + ((kk * 4 + g0) ^ r7) * 8);
      }
      __builtin_amdgcn_s_setprio(1);
      #pragma unroll
      for (int f2 = 0; f2 < 2; ++f2)
        #pragma unroll
        for (int j = 0; j < 4; ++j)
          #pragma unroll
          for (int kk = 0; kk < 2; ++kk)
            MFMAH(acc[fp * 2 + f2][j], af[f2][kk], bf[j][kk]);
      __builtin_amdgcn_s_setprio(0);
    }
    asm volatile("s_waitcnt lgkmcnt(0)" ::: "memory");
    __builtin_amdgcn_sched_barrier(0);
    __builtin_amdgcn_s_barrier();
  }

  // epilogue: C/D layout col=lane&15, row=(lane>>4)*4+q (m89/m91 verified)
  const int lr = (lane >> 4) * 4;
  const int lc = lane & 15;
  #pragma unroll
  for (int f = 0; f < 8; ++f)
    #pragma unroll
    for (int j = 0; j < 4; ++j)
      #pragma unroll
      for (int q = 0; q < 4; ++q) {
        int rr = m0 + wr + f * 16 + lr + q;
        int cc = n0 + wc + j * 16 + lc;
        float v = acc[f][j][q];
        if constexpr (MODE == 0) {
          unsigned short h = f2hu(v);
          unsigned short l = f2hu(v - hu2f(h));
          outHi[(size_t)rr * 1024 + cc] = h;
          outLo[(size_t)rr * 1024 + cc] = l;
        } else {
          outF[((size_t)rr * 16 + bb) * 1024 + cc] = v;
        }
      }
}

// ---------- SPLIT (2-term) GEMM: r5 ring-3 structure, unchanged ----------
// MODE 1 only: out f32 at (rr*16+bb)*1024+cc
__global__ void __launch_bounds__(512, 2)
gemmU(const unsigned short* __restrict__ Ah, const unsigned short* __restrict__ Al,
      const unsigned short* __restrict__ Bh,
      size_t aBatch, size_t bBatch, int mnShift,
      float* __restrict__ outF) {
  constexpr int OPS = 3;
  constexpr int BUFSTRIDE = OPS * 8192;
  constexpr int NT = 32;
  __shared__ __align__(16) unsigned short lds[3 * BUFSTRIDE];  // 144 KiB

  const int hw = blockIdx.x;
  const int L  = (hw & 7) * 32 + (hw >> 3);
  const int bb = L >> mnShift;
  const int r  = L & ((1 << mnShift) - 1);
  const int m0 = (r >> 2) * 256;
  const int n0 = (r & 3) * 256;

  const int tid  = threadIdx.x;
  const int lane = tid & 63;
  const int w    = tid >> 6;
  const int wr   = (w >> 2) * 128;
  const int wc   = (w & 3) * 64;
  const int l15  = lane & 15;
  const int g0   = lane >> 4;

  const int srow = tid >> 2;
  const int scol = ((tid & 3) ^ ((srow >> 1) & 3)) * 8;
  const unsigned short* sp[3];
  {
    const size_t aOff = (size_t)bb * aBatch + (size_t)(m0 + srow) * 1024 + scol;
    const size_t bOff = (size_t)bb * bBatch + (size_t)(n0 + srow) * 1024 + scol;
    sp[0] = Ah + aOff; sp[1] = Al + aOff; sp[2] = Bh + bOff;
  }

  auto stage_tile = [&](int buf, int kt) {
    #pragma unroll
    for (int op = 0; op < OPS; ++op)
      #pragma unroll
      for (int h = 0; h < 2; ++h) {
        const unsigned short* g = sp[op] + (size_t)h * (128 * 1024) + kt * 32;
        unsigned short* l = lds + buf * BUFSTRIDE + op * 8192 + h * 4096 + tid * 8;
        GLOADLDS(g, l);
      }
  };

  f32x4 acc[8][4];
  const f32x4 vzero = {0.f, 0.f, 0.f, 0.f};
  #pragma unroll
  for (int f = 0; f < 8; ++f)
    #pragma unroll
    for (int j = 0; j < 4; ++j) acc[f][j] = vzero;

  short8 ah[4], al[4], b0[2], b1[2];

  stage_tile(0, 0);
  stage_tile(1, 1);

  #pragma unroll 1
  for (int t = 0; t < NT; ++t) {
    const unsigned short* tb = lds + (t % 3) * BUFSTRIDE;
    const unsigned short* tA = tb;
    const unsigned short* tAl = tb + 8192;
    const unsigned short* tB = tb + 16384;

    stage_tile((t + 2) % 3, (t + 2 < NT) ? (t + 2) : (NT - 1));
    asm volatile("s_waitcnt vmcnt(12)" ::: "memory");
    __builtin_amdgcn_s_barrier();
    asm volatile("" ::: "memory");

    #pragma unroll
    for (int f = 0; f < 4; ++f) {
      ah[f] = fragr(tA, wr + f * 16 + l15, g0);
      al[f] = fragr(tAl, wr + f * 16 + l15, g0);
    }
    #pragma unroll
    for (int j = 0; j < 2; ++j) b0[j] = fragr(tB, wc + j * 16 + l15, g0);
    __builtin_amdgcn_s_setprio(1);
    #pragma unroll
    for (int f = 0; f < 4; ++f)
      #pragma unroll
      for (int j = 0; j < 2; ++j) { MFMAH(acc[f][j], ah[f], b0[j]); MFMAH(acc[f][j], al[f], b0[j]); }
    __builtin_amdgcn_s_setprio(0);

    #pragma unroll
    for (int j = 0; j < 2; ++j) b1[j] = fragr(tB, wc + (j + 2) * 16 + l15, g0);
    __builtin_amdgcn_s_setprio(1);
    #pragma unroll
    for (int f = 0; f < 4; ++f)
      #pragma unroll
      for (int j = 0; j < 2; ++j) { MFMAH(acc[f][j + 2], ah[f], b1[j]); MFMAH(acc[f][j + 2], al[f], b1[j]); }
    __builtin_amdgcn_s_setprio(0);

    #pragma unroll
    for (int f = 0; f < 4; ++f) {
      ah[f] = fragr(tA, wr + 64 + f * 16 + l15, g0);
      al[f] = fragr(tAl, wr + 64 + f * 16 + l15, g0);
    }
    __builtin_amdgcn_s_setprio(1);
    #pragma unroll
    for (int f = 0; f < 4; ++f)
      #pragma unroll
      for (int j = 0; j < 2; ++j) { MFMAH(acc[4 + f][j], ah[f], b0[j]); MFMAH(acc[4 + f][j], al[f], b0[j]); }
    __builtin_amdgcn_s_setprio(0);

    __builtin_amdgcn_s_setprio(1);
    #pragma unroll
    for (int f = 0; f < 4; ++f)
      #pragma unroll
      for (int j = 0; j < 2; ++j) { MFMAH(acc[4 + f][j + 2], ah[f], b1[j]); MFMAH(acc[4 + f][j + 2], al[f], b1[j]); }
    __builtin_amdgcn_s_setprio(0);
    asm volatile("" ::: "memory");
    __builtin_amdgcn_s_barrier();
  }

  const int lr = (lane >> 4) * 4;
  const int lc = lane & 15;
  #pragma unroll
  for (int f = 0; f < 8; ++f)
    #pragma unroll
    for (int j = 0; j < 4; ++j)
      #pragma unroll
      for (int q = 0; q < 4; ++q) {
        int rr = m0 + wr + f * 16 + lr + q;
        int cc = n0 + wc + j * 16 + lc;
        outF[((size_t)rr * 16 + bb) * 1024 + cc] = acc[f][j][q];
      }
}

// ---------- in-place row softmax on [T,B,S] fp32 + fp16 copy to p[B,T,S] ----------
__global__ void __launch_bounds__(256)
softmax_kernel(float* __restrict__ av, unsigned short* __restrict__ p) {
  int row = blockIdx.x;           // row = t*16 + b
  int t = row >> 4, b = row & 15;
  float* a = av + (size_t)row * 1024;
  int tid = threadIdx.x, lane = tid & 63, wid = tid >> 6;
  float4 v = reinterpret_cast<float4*>(a)[tid];
  float mx = fmaxf(fmaxf(v.x, v.y), fmaxf(v.z, v.w));
  #pragma unroll
  for (int o = 1; o < 64; o <<= 1) mx = fmaxf(mx, __shfl_xor(mx, o));
  __shared__ float redM[4], redS[4];
  if (lane == 0) redM[wid] = mx;
  __syncthreads();
  mx = fmaxf(fmaxf(redM[0], redM[1]), fmaxf(redM[2], redM[3]));
  float e0 = __expf(v.x - mx), e1 = __expf(v.y - mx);
  float e2 = __expf(v.z - mx), e3 = __expf(v.w - mx);
  float s = (e0 + e1) + (e2 + e3);
  #pragma unroll
  for (int o = 1; o < 64; o <<= 1) s += __shfl_xor(s, o);
  if (lane == 0) redS[wid] = s;
  __syncthreads();
  s = (redS[0] + redS[1]) + (redS[2] + redS[3]);
  float inv = 1.0f / s;
  float4 o4;
  o4.x = e0 * inv; o4.y = e1 * inv; o4.z = e2 * inv; o4.w = e3 * inv;
  reinterpret_cast<float4*>(a)[tid] = o4;
  ushort4 pb;
  pb.x = f2hu(o4.x); pb.y = f2hu(o4.y); pb.z = f2hu(o4.z); pb.w = f2hu(o4.w);
  reinterpret_cast<ushort4*>(p + ((size_t)b * Tdim + t) * Sdim)[tid] = pb;
}

extern "C" void kernel_launch(void* const* d_in, const int* in_sizes, int n_in,
                              void* d_out, int out_size, void* d_ws, size_t ws_size,
                              hipStream_t stream) {
  const float* input = (const float*)d_in[0];  // [B,T,D]
  const float* ctx   = (const float*)d_in[1];  // [B,S,D]
  const float* Wt    = (const float*)d_in[2];  // [D,D]
  float* attn_out  = (float*)d_out;                               // [T,B,D]
  float* align_out = attn_out + (size_t)Tdim * Bdim * Ddim;       // [T,B,S]

  const size_t NE = (size_t)Bdim * Tdim * Ddim;  // 16M elems
  unsigned short* x16 = (unsigned short*)d_ws;
  unsigned short* Wh  = x16 + NE;
  unsigned short* hh  = Wh + (size_t)Ddim * Ddim;
  unsigned short* hl  = hh + NE;
  unsigned short* ctxT = hl + NE;
  unsigned short* ctx16 = x16;   // after K1, x dead
  unsigned short* p     = hh;    // after K2, h dead

  conv_kernel<<<2048, 256, 0, stream>>>(input, x16, (int)(NE / 4));
  conv_kernel<<<512, 256, 0, stream>>>(Wt, Wh, (int)((size_t)Ddim * Ddim / 4));
  // K1: h = x @ W^T, plain fp16, split OUTPUT (hi/lo from f32 acc)
  gemmP<0><<<256, 512, 0, stream>>>(x16, Wh, 0, 0, 8, hh, hl, nullptr);
  // ctx16 [B,S,D] + ctxT [B,D,S] fp16 (ctx16 into dead x region)
  ctxprep_kernel<<<dim3(16, 16, Bdim), 256, 0, stream>>>(ctx, ctx16, ctxT);
  // K2: align = h @ ctx^T, A=h split (2-term), B=ctx16; out f32 [T,B,S]
  gemmU<<<256, 512, 0, stream>>>(hh, hl, ctx16, (size_t)Tdim * Ddim,
                                 (size_t)Sdim * Ddim, 4, align_out);
  // softmax in-place + p fp16 [B,T,S]
  softmax_kernel<<<Bdim * Tdim, 256, 0, stream>>>(align_out, p);
  // K4: attn = p @ ctx, plain fp16, A=p, B=ctxT; out f32 [T,B,D]
  gemmP<1><<<256, 512, 0, stream>>>(p, ctxT, (size_t)Tdim * Sdim,
                                    (size_t)Ddim * Sdim, 4, nullptr, nullptr, attn_out);
}

// Round 9
// 218.355 us; speedup vs baseline: 1.6098x; 1.0100x over previous
//
#include <hip/hip_runtime.h>
#include <hip/hip_bf16.h>

using short8 = __attribute__((ext_vector_type(8))) short;
using half8  = __attribute__((ext_vector_type(8))) _Float16;
using f32x4  = __attribute__((ext_vector_type(4))) float;

constexpr int Bdim = 16;
constexpr int Tdim = 1024;
constexpr int Sdim = 1024;
constexpr int Ddim = 1024;

__device__ __forceinline__ unsigned short f2hu(float x) {
  _Float16 h = (_Float16)x;
  return __builtin_bit_cast(unsigned short, h);
}
__device__ __forceinline__ float hu2f(unsigned short u) {
  return (float)__builtin_bit_cast(_Float16, u);
}

// ---------- fp32 -> fp16 single ----------
__global__ void __launch_bounds__(256)
conv_kernel(const float* __restrict__ src, unsigned short* __restrict__ dst, int n4) {
  int i = blockIdx.x * blockDim.x + threadIdx.x;
  int stride = gridDim.x * blockDim.x;
  for (; i < n4; i += stride) {
    float4 v = reinterpret_cast<const float4*>(src)[i];
    ushort4 h;
    h.x = f2hu(v.x); h.y = f2hu(v.y); h.z = f2hu(v.z); h.w = f2hu(v.w);
    reinterpret_cast<ushort4*>(dst)[i] = h;
  }
}

// ---------- ctx [B,S,D] fp32 -> ctx16 [B,S,D] fp16 AND ctxT [B,D,S] fp16 ----------
__global__ void __launch_bounds__(256)
ctxprep_kernel(const float* __restrict__ ctx, unsigned short* __restrict__ ctx16,
               unsigned short* __restrict__ ctxT) {
  __shared__ float tile[64][65];
  int b = blockIdx.z;
  int d0 = blockIdx.x * 64, s0 = blockIdx.y * 64;
  const float* src = ctx + (size_t)b * Sdim * Ddim;
  unsigned short* dstS = ctx16 + (size_t)b * Sdim * Ddim;
  unsigned short* dstT = ctxT + (size_t)b * Ddim * Sdim;
  int tx = threadIdx.x & 15, ty = threadIdx.x >> 4;
  #pragma unroll
  for (int r = 0; r < 4; ++r) {
    int s = ty + r * 16;
    float4 v = reinterpret_cast<const float4*>(src + (size_t)(s0 + s) * Ddim + d0)[tx];
    ushort4 hs;
    hs.x = f2hu(v.x); hs.y = f2hu(v.y); hs.z = f2hu(v.z); hs.w = f2hu(v.w);
    reinterpret_cast<ushort4*>(dstS + (size_t)(s0 + s) * Ddim + d0)[tx] = hs;
    tile[s][tx * 4 + 0] = v.x; tile[s][tx * 4 + 1] = v.y;
    tile[s][tx * 4 + 2] = v.z; tile[s][tx * 4 + 3] = v.w;
  }
  __syncthreads();
  #pragma unroll
  for (int r = 0; r < 4; ++r) {
    int d = ty + r * 16;
    ushort4 o;
    o.x = f2hu(tile[tx * 4 + 0][d]);
    o.y = f2hu(tile[tx * 4 + 1][d]);
    o.z = f2hu(tile[tx * 4 + 2][d]);
    o.w = f2hu(tile[tx * 4 + 3][d]);
    reinterpret_cast<ushort4*>(dstT + (size_t)(d0 + d) * Sdim + s0)[tx] = o;
  }
}

#define MFMAH(d, x, y)                                                          \
  d = __builtin_amdgcn_mfma_f32_16x16x32_f16(__builtin_bit_cast(half8, (x)),    \
                                             __builtin_bit_cast(half8, (y)), (d), 0, 0, 0)

#define GLOADLDS(g, l)                                                          \
  __builtin_amdgcn_global_load_lds((const __attribute__((address_space(1))) void*)(g), \
                                   (__attribute__((address_space(3))) void*)(l), 16, 0, 0)

// ---------- PLAIN fp16 GEMM: 256x256 tile, BK=64, dbuf 128 KiB, NT=16 ----------
// (unchanged from r8 — K1/K4 at ~48 µs each)
template <int MODE>
__global__ void __launch_bounds__(512, 2)
gemmP(const unsigned short* __restrict__ Ag, const unsigned short* __restrict__ Bg,
      size_t aBatch, size_t bBatch, int mnShift,
      unsigned short* __restrict__ outHi, unsigned short* __restrict__ outLo,
      float* __restrict__ outF) {
  constexpr int NT = 16;
  __shared__ __align__(16) unsigned short lds[2 * 2 * 16384];  // [buf][op][256*64]

  const int hw = blockIdx.x;
  const int L  = (hw & 7) * 32 + (hw >> 3);
  const int bb = L >> mnShift;
  const int r  = L & ((1 << mnShift) - 1);
  const int m0 = (r >> 2) * 256;
  const int n0 = (r & 3) * 256;

  const int tid  = threadIdx.x;
  const int lane = tid & 63;
  const int w    = tid >> 6;          // 8 waves: 2(M) x 4(N)
  const int wr   = (w >> 2) * 128;
  const int wc   = (w & 3) * 64;
  const int l15  = lane & 15;
  const int g0   = lane >> 4;
  const int r7   = l15 & 7;

  const int srow8 = tid >> 3;        // 0..63
  const int sg    = tid & 7;
  const int rs    = srow8 & 7;
  const unsigned short* spA = Ag + (size_t)bb * aBatch + (size_t)(m0 + srow8) * 1024 + ((sg ^ rs) * 8);
  const unsigned short* spB = Bg + (size_t)bb * bBatch + (size_t)(n0 + srow8) * 1024 + ((sg ^ rs) * 8);

  auto stage = [&](int buf, int kt) {
    #pragma unroll
    for (int i = 0; i < 4; ++i) {
      unsigned short* lb = lds + buf * 32768 + (srow8 + i * 64) * 64 + sg * 8;
      GLOADLDS(spA + (size_t)i * (64 * 1024) + kt * 64, lb);
      GLOADLDS(spB + (size_t)i * (64 * 1024) + kt * 64, lb + 16384);
    }
  };

  f32x4 acc[8][4];
  const f32x4 vzero = {0.f, 0.f, 0.f, 0.f};
  #pragma unroll
  for (int f = 0; f < 8; ++f)
    #pragma unroll
    for (int j = 0; j < 4; ++j) acc[f][j] = vzero;

  stage(0, 0);

  #pragma unroll 1
  for (int t = 0; t < NT; ++t) {
    stage((t + 1) & 1, (t + 1 < NT) ? (t + 1) : (NT - 1));
    asm volatile("s_waitcnt vmcnt(8)" ::: "memory");
    __builtin_amdgcn_s_barrier();
    asm volatile("" ::: "memory");
    const unsigned short* tb = lds + (t & 1) * 32768;
    const unsigned short* tB = tb + 16384;

    short8 bf[4][2];
    #pragma unroll
    for (int j = 0; j < 4; ++j)
      #pragma unroll
      for (int kk = 0; kk < 2; ++kk) {
        const int row = wc + j * 16 + l15;
        bf[j][kk] = *reinterpret_cast<const short8*>(tB + row * 64 + ((kk * 4 + g0) ^ r7) * 8);
      }
    #pragma unroll
    for (int fp = 0; fp < 4; ++fp) {
      short8 af[2][2];
      #pragma unroll
      for (int f2 = 0; f2 < 2; ++f2) {
        const int row = wr + (fp * 2 + f2) * 16 + l15;
        #pragma unroll
        for (int kk = 0; kk < 2; ++kk)
          af[f2][kk] = *reinterpret_cast<const short8*>(tb + row * 64 + ((kk * 4 + g0) ^ r7) * 8);
      }
      __builtin_amdgcn_s_setprio(1);
      #pragma unroll
      for (int f2 = 0; f2 < 2; ++f2)
        #pragma unroll
        for (int j = 0; j < 4; ++j)
          #pragma unroll
          for (int kk = 0; kk < 2; ++kk)
            MFMAH(acc[fp * 2 + f2][j], af[f2][kk], bf[j][kk]);
      __builtin_amdgcn_s_setprio(0);
    }
    asm volatile("s_waitcnt lgkmcnt(0)" ::: "memory");
    __builtin_amdgcn_sched_barrier(0);
    __builtin_amdgcn_s_barrier();
  }

  const int lr = (lane >> 4) * 4;
  const int lc = lane & 15;
  #pragma unroll
  for (int f = 0; f < 8; ++f)
    #pragma unroll
    for (int j = 0; j < 4; ++j)
      #pragma unroll
      for (int q = 0; q < 4; ++q) {
        int rr = m0 + wr + f * 16 + lr + q;
        int cc = n0 + wc + j * 16 + lc;
        float v = acc[f][j][q];
        if constexpr (MODE == 0) {
          unsigned short h = f2hu(v);
          unsigned short l = f2hu(v - hu2f(h));
          outHi[(size_t)rr * 1024 + cc] = h;
          outLo[(size_t)rr * 1024 + cc] = l;
        } else {
          outF[((size_t)rr * 16 + bb) * 1024 + cc] = v;
        }
      }
}

// ---------- SPLIT (2-term) GEMM for K2: 256x256, BK=64, NT=16 ----------
// A(hi,lo) double-buffered (128 KiB) + B SINGLE-buffered (32 KiB) = 160 KiB.
// B dbuf replaced by mid-round barrier: all B-reads retire -> stage B(t+1),
// its DMA latency hidden under the MFMA phase. vmcnt(8) = tile t fully arrived.
__global__ void __launch_bounds__(512, 2)
gemmS(const unsigned short* __restrict__ Ah, const unsigned short* __restrict__ Al,
      const unsigned short* __restrict__ Bh,
      size_t aBatch, size_t bBatch, int mnShift,
      float* __restrict__ outF) {
  constexpr int NT = 16;
  __shared__ __align__(16) unsigned short lds[5 * 16384];  // 160 KiB exactly

  const int hw = blockIdx.x;
  const int L  = (hw & 7) * 32 + (hw >> 3);
  const int bb = L >> mnShift;
  const int r  = L & ((1 << mnShift) - 1);
  const int m0 = (r >> 2) * 256;
  const int n0 = (r & 3) * 256;

  const int tid  = threadIdx.x;
  const int lane = tid & 63;
  const int w    = tid >> 6;          // 8 waves: 2(M) x 4(N)
  const int wr   = (w >> 2) * 128;
  const int wc   = (w & 3) * 64;
  const int l15  = lane & 15;
  const int g0   = lane >> 4;
  const int r7   = l15 & 7;

  const int srow8 = tid >> 3;        // 0..63
  const int sg    = tid & 7;
  const int rs    = srow8 & 7;
  const size_t aRow = (size_t)bb * aBatch + (size_t)(m0 + srow8) * 1024 + ((sg ^ rs) * 8);
  const unsigned short* spAh = Ah + aRow;
  const unsigned short* spAl = Al + aRow;
  const unsigned short* spB  = Bh + (size_t)bb * bBatch + (size_t)(n0 + srow8) * 1024 + ((sg ^ rs) * 8);

  auto stageA = [&](int buf, int kt) {       // 8 loads/thread
    #pragma unroll
    for (int i = 0; i < 4; ++i) {
      unsigned short* lb = lds + buf * 32768 + (srow8 + i * 64) * 64 + sg * 8;
      GLOADLDS(spAh + (size_t)i * (64 * 1024) + kt * 64, lb);
      GLOADLDS(spAl + (size_t)i * (64 * 1024) + kt * 64, lb + 16384);
    }
  };
  auto stageB = [&](int kt) {                // 4 loads/thread, single buffer
    #pragma unroll
    for (int i = 0; i < 4; ++i) {
      unsigned short* lb = lds + 65536 + (srow8 + i * 64) * 64 + sg * 8;
      GLOADLDS(spB + (size_t)i * (64 * 1024) + kt * 64, lb);
    }
  };

  f32x4 acc[8][4];
  const f32x4 vzero = {0.f, 0.f, 0.f, 0.f};
  #pragma unroll
  for (int f = 0; f < 8; ++f)
    #pragma unroll
    for (int j = 0; j < 4; ++j) acc[f][j] = vzero;

  // prologue: A(0)->buf0, B(0), nothing else (A(t+1) issued inside round t)
  stageA(0, 0);
  stageB(0);

  #pragma unroll 1
  for (int t = 0; t < NT; ++t) {
    const int tn = (t + 1 < NT) ? t + 1 : NT - 1;
    stageA((t + 1) & 1, tn);
    // outstanding: A(t)[<=8] + B(t)[4] + A(t+1)[8] -> drain tile t exactly
    asm volatile("s_waitcnt vmcnt(8)" ::: "memory");
    __builtin_amdgcn_s_barrier();            // #1: tile t fully in LDS
    asm volatile("" ::: "memory");
    const unsigned short* tA  = lds + (t & 1) * 32768;
    const unsigned short* tAl = tA + 16384;
    const unsigned short* tB  = lds + 65536;

    // all B frags + fp0 A frags
    short8 bf[4][2];
    #pragma unroll
    for (int j = 0; j < 4; ++j)
      #pragma unroll
      for (int kk = 0; kk < 2; ++kk) {
        const int row = wc + j * 16 + l15;
        bf[j][kk] = *reinterpret_cast<const short8*>(tB + row * 64 + ((kk * 4 + g0) ^ r7) * 8);
      }
    short8 ah0[2][2], al0[2][2];
    #pragma unroll
    for (int f2 = 0; f2 < 2; ++f2) {
      const int row = wr + f2 * 16 + l15;
      #pragma unroll
      for (int kk = 0; kk < 2; ++kk) {
        const int po = ((kk * 4 + g0) ^ r7) * 8;
        ah0[f2][kk] = *reinterpret_cast<const short8*>(tA  + row * 64 + po);
        al0[f2][kk] = *reinterpret_cast<const short8*>(tAl + row * 64 + po);
      }
    }
    asm volatile("s_waitcnt lgkmcnt(0)" ::: "memory");
    __builtin_amdgcn_sched_barrier(0);
    __builtin_amdgcn_s_barrier();            // #2: every wave's B(t) reads retired
    stageB(tn);                              // B(t+1) DMA hides under MFMA below
    __builtin_amdgcn_s_setprio(1);
    #pragma unroll
    for (int f2 = 0; f2 < 2; ++f2)
      #pragma unroll
      for (int j = 0; j < 4; ++j)
        #pragma unroll
        for (int kk = 0; kk < 2; ++kk) {
          MFMAH(acc[f2][j], ah0[f2][kk], bf[j][kk]);
          MFMAH(acc[f2][j], al0[f2][kk], bf[j][kk]);
        }
    __builtin_amdgcn_s_setprio(0);

    #pragma unroll
    for (int fp = 1; fp < 4; ++fp) {
      short8 ah[2][2], al[2][2];
      #pragma unroll
      for (int f2 = 0; f2 < 2; ++f2) {
        const int row = wr + (fp * 2 + f2) * 16 + l15;
        #pragma unroll
        for (int kk = 0; kk < 2; ++kk) {
          const int po = ((kk * 4 + g0) ^ r7) * 8;
          ah[f2][kk] = *reinterpret_cast<const short8*>(tA  + row * 64 + po);
          al[f2][kk] = *reinterpret_cast<const short8*>(tAl + row * 64 + po);
        }
      }
      __builtin_amdgcn_s_setprio(1);
      #pragma unroll
      for (int f2 = 0; f2 < 2; ++f2)
        #pragma unroll
        for (int j = 0; j < 4; ++j)
          #pragma unroll
          for (int kk = 0; kk < 2; ++kk) {
            MFMAH(acc[fp * 2 + f2][j], ah[f2][kk], bf[j][kk]);
            MFMAH(acc[fp * 2 + f2][j], al[f2][kk], bf[j][kk]);
          }
      __builtin_amdgcn_s_setprio(0);
    }
    asm volatile("s_waitcnt lgkmcnt(0)" ::: "memory");
    __builtin_amdgcn_sched_barrier(0);
    __builtin_amdgcn_s_barrier();            // #3: A(t) reads retired
  }

  const int lr = (lane >> 4) * 4;
  const int lc = lane & 15;
  #pragma unroll
  for (int f = 0; f < 8; ++f)
    #pragma unroll
    for (int j = 0; j < 4; ++j)
      #pragma unroll
      for (int q = 0; q < 4; ++q) {
        int rr = m0 + wr + f * 16 + lr + q;
        int cc = n0 + wc + j * 16 + lc;
        outF[((size_t)rr * 16 + bb) * 1024 + cc] = acc[f][j][q];
      }
}

// ---------- in-place row softmax on [T,B,S] fp32 + fp16 copy to p[B,T,S] ----------
__global__ void __launch_bounds__(256)
softmax_kernel(float* __restrict__ av, unsigned short* __restrict__ p) {
  int row = blockIdx.x;           // row = t*16 + b
  int t = row >> 4, b = row & 15;
  float* a = av + (size_t)row * 1024;
  int tid = threadIdx.x, lane = tid & 63, wid = tid >> 6;
  float4 v = reinterpret_cast<float4*>(a)[tid];
  float mx = fmaxf(fmaxf(v.x, v.y), fmaxf(v.z, v.w));
  #pragma unroll
  for (int o = 1; o < 64; o <<= 1) mx = fmaxf(mx, __shfl_xor(mx, o));
  __shared__ float redM[4], redS[4];
  if (lane == 0) redM[wid] = mx;
  __syncthreads();
  mx = fmaxf(fmaxf(redM[0], redM[1]), fmaxf(redM[2], redM[3]));
  float e0 = __expf(v.x - mx), e1 = __expf(v.y - mx);
  float e2 = __expf(v.z - mx), e3 = __expf(v.w - mx);
  float s = (e0 + e1) + (e2 + e3);
  #pragma unroll
  for (int o = 1; o < 64; o <<= 1) s += __shfl_xor(s, o);
  if (lane == 0) redS[wid] = s;
  __syncthreads();
  s = (redS[0] + redS[1]) + (redS[2] + redS[3]);
  float inv = 1.0f / s;
  float4 o4;
  o4.x = e0 * inv; o4.y = e1 * inv; o4.z = e2 * inv; o4.w = e3 * inv;
  reinterpret_cast<float4*>(a)[tid] = o4;
  ushort4 pb;
  pb.x = f2hu(o4.x); pb.y = f2hu(o4.y); pb.z = f2hu(o4.z); pb.w = f2hu(o4.w);
  reinterpret_cast<ushort4*>(p + ((size_t)b * Tdim + t) * Sdim)[tid] = pb;
}

extern "C" void kernel_launch(void* const* d_in, const int* in_sizes, int n_in,
                              void* d_out, int out_size, void* d_ws, size_t ws_size,
                              hipStream_t stream) {
  const float* input = (const float*)d_in[0];  // [B,T,D]
  const float* ctx   = (const float*)d_in[1];  // [B,S,D]
  const float* Wt    = (const float*)d_in[2];  // [D,D]
  float* attn_out  = (float*)d_out;                               // [T,B,D]
  float* align_out = attn_out + (size_t)Tdim * Bdim * Ddim;       // [T,B,S]

  const size_t NE = (size_t)Bdim * Tdim * Ddim;  // 16M elems
  unsigned short* x16 = (unsigned short*)d_ws;
  unsigned short* Wh  = x16 + NE;
  unsigned short* hh  = Wh + (size_t)Ddim * Ddim;
  unsigned short* hl  = hh + NE;
  unsigned short* ctxT = hl + NE;
  unsigned short* ctx16 = x16;   // after K1, x dead
  unsigned short* p     = hh;    // after K2, h dead

  conv_kernel<<<2048, 256, 0, stream>>>(input, x16, (int)(NE / 4));
  conv_kernel<<<512, 256, 0, stream>>>(Wt, Wh, (int)((size_t)Ddim * Ddim / 4));
  // K1: h = x @ W^T, plain fp16, split OUTPUT (hi/lo from f32 acc)
  gemmP<0><<<256, 512, 0, stream>>>(x16, Wh, 0, 0, 8, hh, hl, nullptr);
  // ctx16 [B,S,D] + ctxT [B,D,S] fp16 (ctx16 into dead x region)
  ctxprep_kernel<<<dim3(16, 16, Bdim), 256, 0, stream>>>(ctx, ctx16, ctxT);
  // K2: align = h @ ctx^T, A=h split (2-term), B=ctx16; out f32 [T,B,S]
  gemmS<<<256, 512, 0, stream>>>(hh, hl, ctx16, (size_t)Tdim * Ddim,
                                 (size_t)Sdim * Ddim, 4, align_out);
  // softmax in-place + p fp16 [B,T,S]
  softmax_kernel<<<Bdim * Tdim, 256, 0, stream>>>(align_out, p);
  // K4: attn = p @ ctx, plain fp16, A=p, B=ctxT; out f32 [T,B,D]
  gemmP<1><<<256, 512, 0, stream>>>(p, ctxT, (size_t)Tdim * Sdim,
                                    (size_t)Ddim * Sdim, 4, nullptr, nullptr, attn_out);
}

// Round 11
// 187.118 us; speedup vs baseline: 1.8786x; 1.1669x over previous
//
#include <hip/hip_runtime.h>
#include <hip/hip_bf16.h>

using short8 = __attribute__((ext_vector_type(8))) short;
using half8  = __attribute__((ext_vector_type(8))) _Float16;
using f32x4  = __attribute__((ext_vector_type(4))) float;

constexpr int Bdim = 16;
constexpr int Tdim = 1024;
constexpr int Sdim = 1024;
constexpr int Ddim = 1024;

__device__ __forceinline__ unsigned short f2hu(float x) {
  _Float16 h = (_Float16)x;
  return __builtin_bit_cast(unsigned short, h);
}
__device__ __forceinline__ float hu2f(unsigned short u) {
  return (float)__builtin_bit_cast(_Float16, u);
}

// ---------- fp32 -> fp16 single ----------
__global__ void __launch_bounds__(256)
conv_kernel(const float* __restrict__ src, unsigned short* __restrict__ dst, int n4) {
  int i = blockIdx.x * blockDim.x + threadIdx.x;
  int stride = gridDim.x * blockDim.x;
  for (; i < n4; i += stride) {
    float4 v = reinterpret_cast<const float4*>(src)[i];
    ushort4 h;
    h.x = f2hu(v.x); h.y = f2hu(v.y); h.z = f2hu(v.z); h.w = f2hu(v.w);
    reinterpret_cast<ushort4*>(dst)[i] = h;
  }
}

// ---------- ctx [B,S,D] fp32 -> ctx16 [B,S,D] fp16 AND ctxT [B,D,S] fp16 ----------
__global__ void __launch_bounds__(256)
ctxprep_kernel(const float* __restrict__ ctx, unsigned short* __restrict__ ctx16,
               unsigned short* __restrict__ ctxT) {
  __shared__ float tile[64][65];
  int b = blockIdx.z;
  int d0 = blockIdx.x * 64, s0 = blockIdx.y * 64;
  const float* src = ctx + (size_t)b * Sdim * Ddim;
  unsigned short* dstS = ctx16 + (size_t)b * Sdim * Ddim;
  unsigned short* dstT = ctxT + (size_t)b * Ddim * Sdim;
  int tx = threadIdx.x & 15, ty = threadIdx.x >> 4;
  #pragma unroll
  for (int r = 0; r < 4; ++r) {
    int s = ty + r * 16;
    float4 v = reinterpret_cast<const float4*>(src + (size_t)(s0 + s) * Ddim + d0)[tx];
    ushort4 hs;
    hs.x = f2hu(v.x); hs.y = f2hu(v.y); hs.z = f2hu(v.z); hs.w = f2hu(v.w);
    reinterpret_cast<ushort4*>(dstS + (size_t)(s0 + s) * Ddim + d0)[tx] = hs;
    tile[s][tx * 4 + 0] = v.x; tile[s][tx * 4 + 1] = v.y;
    tile[s][tx * 4 + 2] = v.z; tile[s][tx * 4 + 3] = v.w;
  }
  __syncthreads();
  #pragma unroll
  for (int r = 0; r < 4; ++r) {
    int d = ty + r * 16;
    ushort4 o;
    o.x = f2hu(tile[tx * 4 + 0][d]);
    o.y = f2hu(tile[tx * 4 + 1][d]);
    o.z = f2hu(tile[tx * 4 + 2][d]);
    o.w = f2hu(tile[tx * 4 + 3][d]);
    reinterpret_cast<ushort4*>(dstT + (size_t)(d0 + d) * Sdim + s0)[tx] = o;
  }
}

#define MFMAH(d, x, y)                                                          \
  d = __builtin_amdgcn_mfma_f32_16x16x32_f16(__builtin_bit_cast(half8, (x)),    \
                                             __builtin_bit_cast(half8, (y)), (d), 0, 0, 0)

#define GLOADLDS(g, l)                                                          \
  __builtin_amdgcn_global_load_lds((const __attribute__((address_space(1))) void*)(g), \
                                   (__attribute__((address_space(3))) void*)(l), 16, 0, 0)

// ---------- PLAIN fp16 GEMM: 256x256 tile, BK=64, dbuf 128 KiB, NT=16 ----------
// MODE 1: out f32 at (rr*16+bb)*1024+cc ; MODE 2: out fp16 at rr*1024+cc
template <int MODE>
__global__ void __launch_bounds__(512, 2)
gemmP(const unsigned short* __restrict__ Ag, const unsigned short* __restrict__ Bg,
      size_t aBatch, size_t bBatch, int mnShift,
      unsigned short* __restrict__ outH, float* __restrict__ outF) {
  constexpr int NT = 16;
  __shared__ __align__(16) unsigned short lds[2 * 2 * 16384];  // [buf][op][256*64]

  const int hw = blockIdx.x;
  const int L  = (hw & 7) * 32 + (hw >> 3);
  const int bb = L >> mnShift;
  const int r  = L & ((1 << mnShift) - 1);
  const int m0 = (r >> 2) * 256;
  const int n0 = (r & 3) * 256;

  const int tid  = threadIdx.x;
  const int lane = tid & 63;
  const int w    = tid >> 6;          // 8 waves: 2(M) x 4(N)
  const int wr   = (w >> 2) * 128;
  const int wc   = (w & 3) * 64;
  const int l15  = lane & 15;
  const int g0   = lane >> 4;
  const int r7   = l15 & 7;

  const int srow8 = tid >> 3;        // 0..63
  const int sg    = tid & 7;
  const int rs    = srow8 & 7;
  const unsigned short* spA = Ag + (size_t)bb * aBatch + (size_t)(m0 + srow8) * 1024 + ((sg ^ rs) * 8);
  const unsigned short* spB = Bg + (size_t)bb * bBatch + (size_t)(n0 + srow8) * 1024 + ((sg ^ rs) * 8);

  auto stage = [&](int buf, int kt) {
    #pragma unroll
    for (int i = 0; i < 4; ++i) {
      unsigned short* lb = lds + buf * 32768 + (srow8 + i * 64) * 64 + sg * 8;
      GLOADLDS(spA + (size_t)i * (64 * 1024) + kt * 64, lb);
      GLOADLDS(spB + (size_t)i * (64 * 1024) + kt * 64, lb + 16384);
    }
  };

  f32x4 acc[8][4];
  const f32x4 vzero = {0.f, 0.f, 0.f, 0.f};
  #pragma unroll
  for (int f = 0; f < 8; ++f)
    #pragma unroll
    for (int j = 0; j < 4; ++j) acc[f][j] = vzero;

  stage(0, 0);

  #pragma unroll 1
  for (int t = 0; t < NT; ++t) {
    stage((t + 1) & 1, (t + 1 < NT) ? (t + 1) : (NT - 1));
    asm volatile("s_waitcnt vmcnt(8)" ::: "memory");
    __builtin_amdgcn_s_barrier();
    asm volatile("" ::: "memory");
    const unsigned short* tb = lds + (t & 1) * 32768;
    const unsigned short* tB = tb + 16384;

    short8 bf[4][2];
    #pragma unroll
    for (int j = 0; j < 4; ++j)
      #pragma unroll
      for (int kk = 0; kk < 2; ++kk) {
        const int row = wc + j * 16 + l15;
        bf[j][kk] = *reinterpret_cast<const short8*>(tB + row * 64 + ((kk * 4 + g0) ^ r7) * 8);
      }
    #pragma unroll
    for (int fp = 0; fp < 4; ++fp) {
      short8 af[2][2];
      #pragma unroll
      for (int f2 = 0; f2 < 2; ++f2) {
        const int row = wr + (fp * 2 + f2) * 16 + l15;
        #pragma unroll
        for (int kk = 0; kk < 2; ++kk)
          af[f2][kk] = *reinterpret_cast<const short8*>(tb + row * 64 + ((kk * 4 + g0) ^ r7) * 8);
      }
      __builtin_amdgcn_s_setprio(1);
      #pragma unroll
      for (int f2 = 0; f2 < 2; ++f2)
        #pragma unroll
        for (int j = 0; j < 4; ++j)
          #pragma unroll
          for (int kk = 0; kk < 2; ++kk)
            MFMAH(acc[fp * 2 + f2][j], af[f2][kk], bf[j][kk]);
      __builtin_amdgcn_s_setprio(0);
    }
    asm volatile("s_waitcnt lgkmcnt(0)" ::: "memory");
    __builtin_amdgcn_sched_barrier(0);
    __builtin_amdgcn_s_barrier();
  }

  const int lr = (lane >> 4) * 4;
  const int lc = lane & 15;
  #pragma unroll
  for (int f = 0; f < 8; ++f)
    #pragma unroll
    for (int j = 0; j < 4; ++j)
      #pragma unroll
      for (int q = 0; q < 4; ++q) {
        int rr = m0 + wr + f * 16 + lr + q;
        int cc = n0 + wc + j * 16 + lc;
        float v = acc[f][j][q];
        if constexpr (MODE == 2) {
          outH[(size_t)rr * 1024 + cc] = f2hu(v);
        } else {
          outF[((size_t)rr * 16 + bb) * 1024 + cc] = v;
        }
      }
}

// ---------- FUSED K2+softmax: 64x1024 tile (full S row), BK=64, NT=16 ----------
// align[t,b,s] = softmax_s( sum_d h[b,t,d]*ctx[b,s,d] ); also p fp16 [B,T,S].
// LDS: A dbuf 2x8KB + B single 128KB = 144KB. B restaged mid-round under MFMA.
__global__ void __launch_bounds__(512, 2)
gemmF(const unsigned short* __restrict__ Hh, const unsigned short* __restrict__ Cg,
      float* __restrict__ alignOut, unsigned short* __restrict__ pOut) {
  constexpr int NT = 16;
  __shared__ __align__(16) unsigned short lds[2 * 4096 + 65536];  // A dbuf + B

  const int hw = blockIdx.x;                 // 256 blocks
  const int L  = (hw & 7) * 32 + (hw >> 3);  // XCD-chunked
  const int bb = L >> 4;                     // 16 batches
  const int m0 = (L & 15) * 64;              // 16 M-blocks of 64 rows

  const int tid  = threadIdx.x;
  const int lane = tid & 63;
  const int w    = tid >> 6;          // 8 waves: 1(M) x 8(N); wave cols [w*128, w*128+128)
  const int l15  = lane & 15;
  const int g0   = lane >> 4;

  const int srow = tid >> 3;          // 0..63
  const int sg   = tid & 7;
  const int rs   = srow & 7;
  const unsigned short* spA = Hh + (size_t)bb * (Tdim * Ddim) + (size_t)(m0 + srow) * 1024 + ((sg ^ rs) * 8);
  const unsigned short* spB = Cg + (size_t)bb * (Sdim * Ddim) + (size_t)srow * 1024 + ((sg ^ rs) * 8);

  unsigned short* const ldsB = lds + 8192;

  auto stageA = [&](int buf, int kt) {       // 1 instr/thread (8KB tile)
    GLOADLDS(spA + kt * 64, lds + buf * 4096 + tid * 8);
  };
  auto stageB = [&](int kt) {                // 16 instr/thread (128KB)
    #pragma unroll
    for (int i = 0; i < 16; ++i)
      GLOADLDS(spB + (size_t)i * (64 * 1024) + kt * 64, ldsB + i * 4096 + tid * 8);
  };

  f32x4 acc[4][8];
  const f32x4 vzero = {0.f, 0.f, 0.f, 0.f};
  #pragma unroll
  for (int f = 0; f < 4; ++f)
    #pragma unroll
    for (int j = 0; j < 8; ++j) acc[f][j] = vzero;

  // prologue: A(0), B(0), A(1); drain tile 0 (leave A(1) in flight)
  stageA(0, 0);
  stageB(0);
  stageA(1, 1);
  asm volatile("s_waitcnt vmcnt(1)" ::: "memory");
  __builtin_amdgcn_s_barrier();

  #pragma unroll 1
  for (int t = 0; t < NT; ++t) {
    const unsigned short* tA = lds + (t & 1) * 4096;

    // read all frags for this round
    short8 bf[8][2];
    #pragma unroll
    for (int j = 0; j < 8; ++j) {
      const int row = w * 128 + j * 16 + l15;
      #pragma unroll
      for (int kk = 0; kk < 2; ++kk)
        bf[j][kk] = *reinterpret_cast<const short8*>(ldsB + row * 64 + ((kk * 4 + g0) ^ (row & 7)) * 8);
    }
    short8 af[4][2];
    #pragma unroll
    for (int f = 0; f < 4; ++f) {
      const int row = f * 16 + l15;
      #pragma unroll
      for (int kk = 0; kk < 2; ++kk)
        af[f][kk] = *reinterpret_cast<const short8*>(tA + row * 64 + ((kk * 4 + g0) ^ (row & 7)) * 8);
    }
    asm volatile("s_waitcnt lgkmcnt(0)" ::: "memory");
    __builtin_amdgcn_sched_barrier(0);
    __builtin_amdgcn_s_barrier();          // all LDS reads retired -> buffers free

    if (t + 1 < NT) stageB(t + 1);         // restage B under MFMA phase
    if (t + 2 < NT) stageA(t & 1, t + 2);  // FIX r10: (buf, kt) — was swapped

    __builtin_amdgcn_s_setprio(1);
    #pragma unroll
    for (int f = 0; f < 4; ++f)
      #pragma unroll
      for (int j = 0; j < 8; ++j)
        #pragma unroll
        for (int kk = 0; kk < 2; ++kk)
          MFMAH(acc[f][j], af[f][kk], bf[j][kk]);
    __builtin_amdgcn_s_setprio(0);

    if (t + 1 < NT) {
      if (t + 2 < NT) asm volatile("s_waitcnt vmcnt(1)" ::: "memory");
      else            asm volatile("s_waitcnt vmcnt(0)" ::: "memory");
    }
    __builtin_amdgcn_s_barrier();
  }

  // ---- fused row softmax over full S=1024 (rows are block-local in M) ----
  float* red = (float*)lds;                 // reuse A region: [64][8] f32
  const int lr = (lane >> 4) * 4;

  float rmax[4][4];
  #pragma unroll
  for (int f = 0; f < 4; ++f)
    #pragma unroll
    for (int q = 0; q < 4; ++q) {
      float m = acc[f][0][q];
      #pragma unroll
      for (int j = 1; j < 8; ++j) m = fmaxf(m, acc[f][j][q]);
      #pragma unroll
      for (int o = 1; o < 16; o <<= 1) m = fmaxf(m, __shfl_xor(m, o));
      rmax[f][q] = m;
    }
  if (l15 == 0) {
    #pragma unroll
    for (int f = 0; f < 4; ++f)
      #pragma unroll
      for (int q = 0; q < 4; ++q) red[(f * 16 + lr + q) * 8 + w] = rmax[f][q];
  }
  __syncthreads();
  #pragma unroll
  for (int f = 0; f < 4; ++f)
    #pragma unroll
    for (int q = 0; q < 4; ++q) {
      const float* rr = red + (f * 16 + lr + q) * 8;
      float m = rr[0];
      #pragma unroll
      for (int k = 1; k < 8; ++k) m = fmaxf(m, rr[k]);
      rmax[f][q] = m;
    }
  __syncthreads();

  float rsum[4][4];
  #pragma unroll
  for (int f = 0; f < 4; ++f)
    #pragma unroll
    for (int q = 0; q < 4; ++q) {
      float s = 0.f;
      #pragma unroll
      for (int j = 0; j < 8; ++j) {
        float e = __expf(acc[f][j][q] - rmax[f][q]);
        acc[f][j][q] = e;
        s += e;
      }
      #pragma unroll
      for (int o = 1; o < 16; o <<= 1) s += __shfl_xor(s, o);
      rsum[f][q] = s;
    }
  if (l15 == 0) {
    #pragma unroll
    for (int f = 0; f < 4; ++f)
      #pragma unroll
      for (int q = 0; q < 4; ++q) red[(f * 16 + lr + q) * 8 + w] = rsum[f][q];
  }
  __syncthreads();
  #pragma unroll
  for (int f = 0; f < 4; ++f)
    #pragma unroll
    for (int q = 0; q < 4; ++q) {
      const float* rr = red + (f * 16 + lr + q) * 8;
      float s = ((rr[0] + rr[1]) + (rr[2] + rr[3])) + ((rr[4] + rr[5]) + (rr[6] + rr[7]));
      rsum[f][q] = 1.0f / s;
    }

  // write align f32 [T,B,S] and p fp16 [B,T,S]
  #pragma unroll
  for (int f = 0; f < 4; ++f)
    #pragma unroll
    for (int q = 0; q < 4; ++q) {
      const int row = m0 + f * 16 + lr + q;
      float inv = rsum[f][q];
      #pragma unroll
      for (int j = 0; j < 8; ++j) {
        const int cc = w * 128 + j * 16 + l15;
        float v = acc[f][j][q] * inv;
        alignOut[((size_t)row * 16 + bb) * 1024 + cc] = v;
        pOut[((size_t)bb * 1024 + row) * 1024 + cc] = f2hu(v);
      }
    }
}

extern "C" void kernel_launch(void* const* d_in, const int* in_sizes, int n_in,
                              void* d_out, int out_size, void* d_ws, size_t ws_size,
                              hipStream_t stream) {
  const float* input = (const float*)d_in[0];  // [B,T,D]
  const float* ctx   = (const float*)d_in[1];  // [B,S,D]
  const float* Wt    = (const float*)d_in[2];  // [D,D]
  float* attn_out  = (float*)d_out;                               // [T,B,D]
  float* align_out = attn_out + (size_t)Tdim * Bdim * Ddim;       // [T,B,S]

  const size_t NE = (size_t)Bdim * Tdim * Ddim;  // 16M elems
  unsigned short* x16  = (unsigned short*)d_ws;  // 32MB, reused as ctx16 after K1
  unsigned short* Wh   = x16 + NE;               // 2MB
  unsigned short* hh   = Wh + (size_t)Ddim * Ddim;  // 32MB, overwritten by p in gemmF
  unsigned short* ctxT = hh + NE;                // 32MB
  unsigned short* ctx16 = x16;
  unsigned short* p     = hh;

  conv_kernel<<<2048, 256, 0, stream>>>(input, x16, (int)(NE / 4));
  conv_kernel<<<512, 256, 0, stream>>>(Wt, Wh, (int)((size_t)Ddim * Ddim / 4));
  // K1: h = x @ W^T, plain fp16 -> hh
  gemmP<2><<<256, 512, 0, stream>>>(x16, Wh, 0, 0, 8, hh, nullptr);
  // ctx16 [B,S,D] + ctxT [B,D,S] fp16 (ctx16 into dead x region)
  ctxprep_kernel<<<dim3(16, 16, Bdim), 256, 0, stream>>>(ctx, ctx16, ctxT);
  // K2 fused: align = softmax(h @ ctx^T) -> align_out f32 [T,B,S], p fp16 (in-place over hh)
  gemmF<<<256, 512, 0, stream>>>(hh, ctx16, align_out, p);
  // K4: attn = p @ ctx, plain fp16 -> f32 [T,B,D]
  gemmP<1><<<256, 512, 0, stream>>>(p, ctxT, (size_t)Tdim * Sdim,
                                    (size_t)Ddim * Sdim, 4, nullptr, attn_out);
}

// Round 12
// 186.908 us; speedup vs baseline: 1.8807x; 1.0011x over previous
//
#include <hip/hip_runtime.h>
#include <hip/hip_bf16.h>

using short8 = __attribute__((ext_vector_type(8))) short;
using half8  = __attribute__((ext_vector_type(8))) _Float16;
using f32x4  = __attribute__((ext_vector_type(4))) float;

constexpr int Bdim = 16;
constexpr int Tdim = 1024;
constexpr int Sdim = 1024;
constexpr int Ddim = 1024;

__device__ __forceinline__ unsigned short f2hu(float x) {
  _Float16 h = (_Float16)x;
  return __builtin_bit_cast(unsigned short, h);
}
__device__ __forceinline__ float hu2f(unsigned short u) {
  return (float)__builtin_bit_cast(_Float16, u);
}

// ---------- fp32 -> fp16 single ----------
__global__ void __launch_bounds__(256)
conv_kernel(const float* __restrict__ src, unsigned short* __restrict__ dst, int n4) {
  int i = blockIdx.x * blockDim.x + threadIdx.x;
  int stride = gridDim.x * blockDim.x;
  for (; i < n4; i += stride) {
    float4 v = reinterpret_cast<const float4*>(src)[i];
    ushort4 h;
    h.x = f2hu(v.x); h.y = f2hu(v.y); h.z = f2hu(v.z); h.w = f2hu(v.w);
    reinterpret_cast<ushort4*>(dst)[i] = h;
  }
}

// ---------- ctx [B,S,D] fp32 -> ctx16 [B,S,D] fp16 AND ctxT [B,D,S] fp16 ----------
__global__ void __launch_bounds__(256)
ctxprep_kernel(const float* __restrict__ ctx, unsigned short* __restrict__ ctx16,
               unsigned short* __restrict__ ctxT) {
  __shared__ float tile[64][65];
  int b = blockIdx.z;
  int d0 = blockIdx.x * 64, s0 = blockIdx.y * 64;
  const float* src = ctx + (size_t)b * Sdim * Ddim;
  unsigned short* dstS = ctx16 + (size_t)b * Sdim * Ddim;
  unsigned short* dstT = ctxT + (size_t)b * Ddim * Sdim;
  int tx = threadIdx.x & 15, ty = threadIdx.x >> 4;
  #pragma unroll
  for (int r = 0; r < 4; ++r) {
    int s = ty + r * 16;
    float4 v = reinterpret_cast<const float4*>(src + (size_t)(s0 + s) * Ddim + d0)[tx];
    ushort4 hs;
    hs.x = f2hu(v.x); hs.y = f2hu(v.y); hs.z = f2hu(v.z); hs.w = f2hu(v.w);
    reinterpret_cast<ushort4*>(dstS + (size_t)(s0 + s) * Ddim + d0)[tx] = hs;
    tile[s][tx * 4 + 0] = v.x; tile[s][tx * 4 + 1] = v.y;
    tile[s][tx * 4 + 2] = v.z; tile[s][tx * 4 + 3] = v.w;
  }
  __syncthreads();
  #pragma unroll
  for (int r = 0; r < 4; ++r) {
    int d = ty + r * 16;
    ushort4 o;
    o.x = f2hu(tile[tx * 4 + 0][d]);
    o.y = f2hu(tile[tx * 4 + 1][d]);
    o.z = f2hu(tile[tx * 4 + 2][d]);
    o.w = f2hu(tile[tx * 4 + 3][d]);
    reinterpret_cast<ushort4*>(dstT + (size_t)(d0 + d) * Sdim + s0)[tx] = o;
  }
}

#define MFMAH(d, x, y)                                                          \
  d = __builtin_amdgcn_mfma_f32_16x16x32_f16(__builtin_bit_cast(half8, (x)),    \
                                             __builtin_bit_cast(half8, (y)), (d), 0, 0, 0)

#define GLOADLDS(g, l)                                                          \
  __builtin_amdgcn_global_load_lds((const __attribute__((address_space(1))) void*)(g), \
                                   (__attribute__((address_space(3))) void*)(l), 16, 0, 0)

// ---------- PLAIN fp16 GEMM: 256x256 tile, BK=64, dbuf 128 KiB, NT=16 ----------
// r12: wait-at-END structure (gemmF-style): read all frags -> barrier ->
// stage t+2 into just-freed buffer UNDER the MFMA phase -> vmcnt(8) -> barrier.
// MODE 1: out f32 at (rr*16+bb)*1024+cc ; MODE 2: out fp16 at rr*1024+cc
template <int MODE>
__global__ void __launch_bounds__(512, 2)
gemmP(const unsigned short* __restrict__ Ag, const unsigned short* __restrict__ Bg,
      size_t aBatch, size_t bBatch, int mnShift,
      unsigned short* __restrict__ outH, float* __restrict__ outF) {
  constexpr int NT = 16;
  __shared__ __align__(16) unsigned short lds[2 * 2 * 16384];  // [buf][op][256*64]

  const int hw = blockIdx.x;
  const int L  = (hw & 7) * 32 + (hw >> 3);
  const int bb = L >> mnShift;
  const int r  = L & ((1 << mnShift) - 1);
  const int m0 = (r >> 2) * 256;
  const int n0 = (r & 3) * 256;

  const int tid  = threadIdx.x;
  const int lane = tid & 63;
  const int w    = tid >> 6;          // 8 waves: 2(M) x 4(N)
  const int wr   = (w >> 2) * 128;
  const int wc   = (w & 3) * 64;
  const int l15  = lane & 15;
  const int g0   = lane >> 4;
  const int r7   = l15 & 7;

  const int srow8 = tid >> 3;        // 0..63
  const int sg    = tid & 7;
  const int rs    = srow8 & 7;
  const unsigned short* spA = Ag + (size_t)bb * aBatch + (size_t)(m0 + srow8) * 1024 + ((sg ^ rs) * 8);
  const unsigned short* spB = Bg + (size_t)bb * bBatch + (size_t)(n0 + srow8) * 1024 + ((sg ^ rs) * 8);

  auto stage = [&](int buf, int kt) {
    #pragma unroll
    for (int i = 0; i < 4; ++i) {
      unsigned short* lb = lds + buf * 32768 + (srow8 + i * 64) * 64 + sg * 8;
      GLOADLDS(spA + (size_t)i * (64 * 1024) + kt * 64, lb);
      GLOADLDS(spB + (size_t)i * (64 * 1024) + kt * 64, lb + 16384);
    }
  };

  f32x4 acc[8][4];
  const f32x4 vzero = {0.f, 0.f, 0.f, 0.f};
  #pragma unroll
  for (int f = 0; f < 8; ++f)
    #pragma unroll
    for (int j = 0; j < 4; ++j) acc[f][j] = vzero;

  // prologue: tiles 0,1 staged; drain tile 0 (leave tile 1 in flight)
  stage(0, 0);
  stage(1, 1);
  asm volatile("s_waitcnt vmcnt(8)" ::: "memory");
  __builtin_amdgcn_s_barrier();

  #pragma unroll 1
  for (int t = 0; t < NT; ++t) {
    const unsigned short* tb = lds + (t & 1) * 32768;
    const unsigned short* tB = tb + 16384;

    // read ALL frags of tile t up front (B 8, A 16 ds_read_b128)
    short8 bf[4][2], af[8][2];
    #pragma unroll
    for (int j = 0; j < 4; ++j)
      #pragma unroll
      for (int kk = 0; kk < 2; ++kk) {
        const int row = wc + j * 16 + l15;
        bf[j][kk] = *reinterpret_cast<const short8*>(tB + row * 64 + ((kk * 4 + g0) ^ r7) * 8);
      }
    #pragma unroll
    for (int f = 0; f < 8; ++f)
      #pragma unroll
      for (int kk = 0; kk < 2; ++kk) {
        const int row = wr + f * 16 + l15;
        af[f][kk] = *reinterpret_cast<const short8*>(tb + row * 64 + ((kk * 4 + g0) ^ r7) * 8);
      }
    asm volatile("s_waitcnt lgkmcnt(0)" ::: "memory");
    __builtin_amdgcn_sched_barrier(0);
    __builtin_amdgcn_s_barrier();           // all reads retired -> buffer free

    if (t + 2 < NT) stage(t & 1, t + 2);    // stage t+2 into freed buffer, under MFMA

    __builtin_amdgcn_s_setprio(1);
    #pragma unroll
    for (int f = 0; f < 8; ++f)
      #pragma unroll
      for (int j = 0; j < 4; ++j)
        #pragma unroll
        for (int kk = 0; kk < 2; ++kk)
          MFMAH(acc[f][j], af[f][kk], bf[j][kk]);
    __builtin_amdgcn_s_setprio(0);
    __builtin_amdgcn_sched_barrier(0);

    // end-of-round wait: drain t+1 (needed next round), keep t+2 in flight
    if (t + 2 < NT) asm volatile("s_waitcnt vmcnt(8)" ::: "memory");
    else            asm volatile("s_waitcnt vmcnt(0)" ::: "memory");
    __builtin_amdgcn_s_barrier();
  }

  const int lr = (lane >> 4) * 4;
  const int lc = lane & 15;
  #pragma unroll
  for (int f = 0; f < 8; ++f)
    #pragma unroll
    for (int j = 0; j < 4; ++j)
      #pragma unroll
      for (int q = 0; q < 4; ++q) {
        int rr = m0 + wr + f * 16 + lr + q;
        int cc = n0 + wc + j * 16 + lc;
        float v = acc[f][j][q];
        if constexpr (MODE == 2) {
          outH[(size_t)rr * 1024 + cc] = f2hu(v);
        } else {
          outF[((size_t)rr * 16 + bb) * 1024 + cc] = v;
        }
      }
}

// ---------- FUSED K2+softmax: 64x1024 tile (full S row), BK=64, NT=16 ----------
// (unchanged from r11 — verified passing)
__global__ void __launch_bounds__(512, 2)
gemmF(const unsigned short* __restrict__ Hh, const unsigned short* __restrict__ Cg,
      float* __restrict__ alignOut, unsigned short* __restrict__ pOut) {
  constexpr int NT = 16;
  __shared__ __align__(16) unsigned short lds[2 * 4096 + 65536];  // A dbuf + B

  const int hw = blockIdx.x;                 // 256 blocks
  const int L  = (hw & 7) * 32 + (hw >> 3);  // XCD-chunked
  const int bb = L >> 4;                     // 16 batches
  const int m0 = (L & 15) * 64;              // 16 M-blocks of 64 rows

  const int tid  = threadIdx.x;
  const int lane = tid & 63;
  const int w    = tid >> 6;          // 8 waves: 1(M) x 8(N)
  const int l15  = lane & 15;
  const int g0   = lane >> 4;

  const int srow = tid >> 3;          // 0..63
  const int sg   = tid & 7;
  const int rs   = srow & 7;
  const unsigned short* spA = Hh + (size_t)bb * (Tdim * Ddim) + (size_t)(m0 + srow) * 1024 + ((sg ^ rs) * 8);
  const unsigned short* spB = Cg + (size_t)bb * (Sdim * Ddim) + (size_t)srow * 1024 + ((sg ^ rs) * 8);

  unsigned short* const ldsB = lds + 8192;

  auto stageA = [&](int buf, int kt) {       // 1 instr/thread (8KB tile)
    GLOADLDS(spA + kt * 64, lds + buf * 4096 + tid * 8);
  };
  auto stageB = [&](int kt) {                // 16 instr/thread (128KB)
    #pragma unroll
    for (int i = 0; i < 16; ++i)
      GLOADLDS(spB + (size_t)i * (64 * 1024) + kt * 64, ldsB + i * 4096 + tid * 8);
  };

  f32x4 acc[4][8];
  const f32x4 vzero = {0.f, 0.f, 0.f, 0.f};
  #pragma unroll
  for (int f = 0; f < 4; ++f)
    #pragma unroll
    for (int j = 0; j < 8; ++j) acc[f][j] = vzero;

  stageA(0, 0);
  stageB(0);
  stageA(1, 1);
  asm volatile("s_waitcnt vmcnt(1)" ::: "memory");
  __builtin_amdgcn_s_barrier();

  #pragma unroll 1
  for (int t = 0; t < NT; ++t) {
    const unsigned short* tA = lds + (t & 1) * 4096;

    short8 bf[8][2];
    #pragma unroll
    for (int j = 0; j < 8; ++j) {
      const int row = w * 128 + j * 16 + l15;
      #pragma unroll
      for (int kk = 0; kk < 2; ++kk)
        bf[j][kk] = *reinterpret_cast<const short8*>(ldsB + row * 64 + ((kk * 4 + g0) ^ (row & 7)) * 8);
    }
    short8 af[4][2];
    #pragma unroll
    for (int f = 0; f < 4; ++f) {
      const int row = f * 16 + l15;
      #pragma unroll
      for (int kk = 0; kk < 2; ++kk)
        af[f][kk] = *reinterpret_cast<const short8*>(tA + row * 64 + ((kk * 4 + g0) ^ (row & 7)) * 8);
    }
    asm volatile("s_waitcnt lgkmcnt(0)" ::: "memory");
    __builtin_amdgcn_sched_barrier(0);
    __builtin_amdgcn_s_barrier();          // all LDS reads retired -> buffers free

    if (t + 1 < NT) stageB(t + 1);         // restage B under MFMA phase
    if (t + 2 < NT) stageA(t & 1, t + 2);

    __builtin_amdgcn_s_setprio(1);
    #pragma unroll
    for (int f = 0; f < 4; ++f)
      #pragma unroll
      for (int j = 0; j < 8; ++j)
        #pragma unroll
        for (int kk = 0; kk < 2; ++kk)
          MFMAH(acc[f][j], af[f][kk], bf[j][kk]);
    __builtin_amdgcn_s_setprio(0);

    if (t + 1 < NT) {
      if (t + 2 < NT) asm volatile("s_waitcnt vmcnt(1)" ::: "memory");
      else            asm volatile("s_waitcnt vmcnt(0)" ::: "memory");
    }
    __builtin_amdgcn_s_barrier();
  }

  // ---- fused row softmax over full S=1024 ----
  float* red = (float*)lds;                 // reuse A region: [64][8] f32
  const int lr = (lane >> 4) * 4;

  float rmax[4][4];
  #pragma unroll
  for (int f = 0; f < 4; ++f)
    #pragma unroll
    for (int q = 0; q < 4; ++q) {
      float m = acc[f][0][q];
      #pragma unroll
      for (int j = 1; j < 8; ++j) m = fmaxf(m, acc[f][j][q]);
      #pragma unroll
      for (int o = 1; o < 16; o <<= 1) m = fmaxf(m, __shfl_xor(m, o));
      rmax[f][q] = m;
    }
  if (l15 == 0) {
    #pragma unroll
    for (int f = 0; f < 4; ++f)
      #pragma unroll
      for (int q = 0; q < 4; ++q) red[(f * 16 + lr + q) * 8 + w] = rmax[f][q];
  }
  __syncthreads();
  #pragma unroll
  for (int f = 0; f < 4; ++f)
    #pragma unroll
    for (int q = 0; q < 4; ++q) {
      const float* rr = red + (f * 16 + lr + q) * 8;
      float m = rr[0];
      #pragma unroll
      for (int k = 1; k < 8; ++k) m = fmaxf(m, rr[k]);
      rmax[f][q] = m;
    }
  __syncthreads();

  float rsum[4][4];
  #pragma unroll
  for (int f = 0; f < 4; ++f)
    #pragma unroll
    for (int q = 0; q < 4; ++q) {
      float s = 0.f;
      #pragma unroll
      for (int j = 0; j < 8; ++j) {
        float e = __expf(acc[f][j][q] - rmax[f][q]);
        acc[f][j][q] = e;
        s += e;
      }
      #pragma unroll
      for (int o = 1; o < 16; o <<= 1) s += __shfl_xor(s, o);
      rsum[f][q] = s;
    }
  if (l15 == 0) {
    #pragma unroll
    for (int f = 0; f < 4; ++f)
      #pragma unroll
      for (int q = 0; q < 4; ++q) red[(f * 16 + lr + q) * 8 + w] = rsum[f][q];
  }
  __syncthreads();
  #pragma unroll
  for (int f = 0; f < 4; ++f)
    #pragma unroll
    for (int q = 0; q < 4; ++q) {
      const float* rr = red + (f * 16 + lr + q) * 8;
      float s = ((rr[0] + rr[1]) + (rr[2] + rr[3])) + ((rr[4] + rr[5]) + (rr[6] + rr[7]));
      rsum[f][q] = 1.0f / s;
    }

  #pragma unroll
  for (int f = 0; f < 4; ++f)
    #pragma unroll
    for (int q = 0; q < 4; ++q) {
      const int row = m0 + f * 16 + lr + q;
      float inv = rsum[f][q];
      #pragma unroll
      for (int j = 0; j < 8; ++j) {
        const int cc = w * 128 + j * 16 + l15;
        float v = acc[f][j][q] * inv;
        alignOut[((size_t)row * 16 + bb) * 1024 + cc] = v;
        pOut[((size_t)bb * 1024 + row) * 1024 + cc] = f2hu(v);
      }
    }
}

extern "C" void kernel_launch(void* const* d_in, const int* in_sizes, int n_in,
                              void* d_out, int out_size, void* d_ws, size_t ws_size,
                              hipStream_t stream) {
  const float* input = (const float*)d_in[0];  // [B,T,D]
  const float* ctx   = (const float*)d_in[1];  // [B,S,D]
  const float* Wt    = (const float*)d_in[2];  // [D,D]
  float* attn_out  = (float*)d_out;                               // [T,B,D]
  float* align_out = attn_out + (size_t)Tdim * Bdim * Ddim;       // [T,B,S]

  const size_t NE = (size_t)Bdim * Tdim * Ddim;  // 16M elems
  unsigned short* x16  = (unsigned short*)d_ws;  // 32MB, reused as ctx16 after K1
  unsigned short* Wh   = x16 + NE;               // 2MB
  unsigned short* hh   = Wh + (size_t)Ddim * Ddim;  // 32MB, overwritten by p in gemmF
  unsigned short* ctxT = hh + NE;                // 32MB
  unsigned short* ctx16 = x16;
  unsigned short* p     = hh;

  conv_kernel<<<2048, 256, 0, stream>>>(input, x16, (int)(NE / 4));
  conv_kernel<<<512, 256, 0, stream>>>(Wt, Wh, (int)((size_t)Ddim * Ddim / 4));
  // K1: h = x @ W^T, plain fp16 -> hh
  gemmP<2><<<256, 512, 0, stream>>>(x16, Wh, 0, 0, 8, hh, nullptr);
  // ctx16 [B,S,D] + ctxT [B,D,S] fp16 (ctx16 into dead x region)
  ctxprep_kernel<<<dim3(16, 16, Bdim), 256, 0, stream>>>(ctx, ctx16, ctxT);
  // K2 fused: align = softmax(h @ ctx^T) -> align_out f32 [T,B,S], p fp16
  gemmF<<<256, 512, 0, stream>>>(hh, ctx16, align_out, p);
  // K4: attn = p @ ctx, plain fp16 -> f32 [T,B,D]
  gemmP<1><<<256, 512, 0, stream>>>(p, ctxT, (size_t)Tdim * Sdim,
                                    (size_t)Ddim * Sdim, 4, nullptr, attn_out);
}

// Round 13
// 182.824 us; speedup vs baseline: 1.9227x; 1.0223x over previous
//
#include <hip/hip_runtime.h>
#include <hip/hip_bf16.h>

using short8 = __attribute__((ext_vector_type(8))) short;
using half8  = __attribute__((ext_vector_type(8))) _Float16;
using f32x4  = __attribute__((ext_vector_type(4))) float;

constexpr int Bdim = 16;
constexpr int Tdim = 1024;
constexpr int Sdim = 1024;
constexpr int Ddim = 1024;

__device__ __forceinline__ unsigned short f2hu(float x) {
  _Float16 h = (_Float16)x;
  return __builtin_bit_cast(unsigned short, h);
}
__device__ __forceinline__ float hu2f(unsigned short u) {
  return (float)__builtin_bit_cast(_Float16, u);
}

// ---------- fp32 -> fp16 single ----------
__global__ void __launch_bounds__(256)
conv_kernel(const float* __restrict__ src, unsigned short* __restrict__ dst, int n4) {
  int i = blockIdx.x * blockDim.x + threadIdx.x;
  int stride = gridDim.x * blockDim.x;
  for (; i < n4; i += stride) {
    float4 v = reinterpret_cast<const float4*>(src)[i];
    ushort4 h;
    h.x = f2hu(v.x); h.y = f2hu(v.y); h.z = f2hu(v.z); h.w = f2hu(v.w);
    reinterpret_cast<ushort4*>(dst)[i] = h;
  }
}

// ---------- ctx [B,S,D] fp32 -> ctx16 [B,S,D] fp16 AND ctxT [B,D,S] fp16 ----------
__global__ void __launch_bounds__(256)
ctxprep_kernel(const float* __restrict__ ctx, unsigned short* __restrict__ ctx16,
               unsigned short* __restrict__ ctxT) {
  __shared__ float tile[64][65];
  int b = blockIdx.z;
  int d0 = blockIdx.x * 64, s0 = blockIdx.y * 64;
  const float* src = ctx + (size_t)b * Sdim * Ddim;
  unsigned short* dstS = ctx16 + (size_t)b * Sdim * Ddim;
  unsigned short* dstT = ctxT + (size_t)b * Ddim * Sdim;
  int tx = threadIdx.x & 15, ty = threadIdx.x >> 4;
  #pragma unroll
  for (int r = 0; r < 4; ++r) {
    int s = ty + r * 16;
    float4 v = reinterpret_cast<const float4*>(src + (size_t)(s0 + s) * Ddim + d0)[tx];
    ushort4 hs;
    hs.x = f2hu(v.x); hs.y = f2hu(v.y); hs.z = f2hu(v.z); hs.w = f2hu(v.w);
    reinterpret_cast<ushort4*>(dstS + (size_t)(s0 + s) * Ddim + d0)[tx] = hs;
    tile[s][tx * 4 + 0] = v.x; tile[s][tx * 4 + 1] = v.y;
    tile[s][tx * 4 + 2] = v.z; tile[s][tx * 4 + 3] = v.w;
  }
  __syncthreads();
  #pragma unroll
  for (int r = 0; r < 4; ++r) {
    int d = ty + r * 16;
    ushort4 o;
    o.x = f2hu(tile[tx * 4 + 0][d]);
    o.y = f2hu(tile[tx * 4 + 1][d]);
    o.z = f2hu(tile[tx * 4 + 2][d]);
    o.w = f2hu(tile[tx * 4 + 3][d]);
    reinterpret_cast<ushort4*>(dstT + (size_t)(d0 + d) * Sdim + s0)[tx] = o;
  }
}

#define MFMAH(d, x, y)                                                          \
  d = __builtin_amdgcn_mfma_f32_16x16x32_f16(__builtin_bit_cast(half8, (x)),    \
                                             __builtin_bit_cast(half8, (y)), (d), 0, 0, 0)

#define GLOADLDS(g, l)                                                          \
  __builtin_amdgcn_global_load_lds((const __attribute__((address_space(1))) void*)(g), \
                                   (__attribute__((address_space(3))) void*)(l), 16, 0, 0)

// ---------- PLAIN fp16 GEMM: 256x256 tile, BK=128, SINGLE 128 KiB buffer, NT=8 ----------
// Round: wait t -> read kk0/1 frags -> MFMA -> read kk2/3 frags -> barrier(all reads
// retired) -> restage t+1 into same buffer -> MFMA under DMA.
// 256B rows, 16 granules; swizzle pg = g ^ (row&15) (full XOR perm per 16 lanes).
// MODE 1: out f32 at (rr*16+bb)*1024+cc ; MODE 2: out fp16 at rr*1024+cc
template <int MODE>
__global__ void __launch_bounds__(512, 2)
gemmP(const unsigned short* __restrict__ Ag, const unsigned short* __restrict__ Bg,
      size_t aBatch, size_t bBatch, int mnShift,
      unsigned short* __restrict__ outH, float* __restrict__ outF) {
  constexpr int NT = 8;                              // BK = 128
  __shared__ __align__(16) unsigned short lds[65536]; // A[256][128] | B[256][128]

  const int hw = blockIdx.x;
  const int L  = (hw & 7) * 32 + (hw >> 3);
  const int bb = L >> mnShift;
  const int r  = L & ((1 << mnShift) - 1);
  const int m0 = (r >> 2) * 256;
  const int n0 = (r & 3) * 256;

  const int tid  = threadIdx.x;
  const int lane = tid & 63;
  const int w    = tid >> 6;          // 8 waves: 2(M) x 4(N)
  const int wr   = (w >> 2) * 128;
  const int wc   = (w & 3) * 64;
  const int l15  = lane & 15;
  const int g0   = lane >> 4;

  // staging: thread covers granule (srow16 + i*32, sg); row&15 == srow16&15 (i*32≡0 mod 16)
  const int srow16 = tid >> 4;        // 0..31
  const int sg     = tid & 15;
  const int rs     = srow16 & 15;
  const unsigned short* spA = Ag + (size_t)bb * aBatch + (size_t)(m0 + srow16) * 1024 + ((sg ^ rs) * 8);
  const unsigned short* spB = Bg + (size_t)bb * bBatch + (size_t)(n0 + srow16) * 1024 + ((sg ^ rs) * 8);
  unsigned short* const ldA = lds + srow16 * 128 + sg * 8;          // linear dest (DMA req)
  unsigned short* const ldB = ldA + 32768;

  auto stage = [&](int kt) {          // 16 loads/thread = full 128 KB tile
    #pragma unroll
    for (int i = 0; i < 8; ++i) {
      GLOADLDS(spA + (size_t)i * (32 * 1024) + kt * 128, ldA + i * 4096);
      GLOADLDS(spB + (size_t)i * (32 * 1024) + kt * 128, ldB + i * 4096);
    }
  };

  f32x4 acc[8][4];
  const f32x4 vzero = {0.f, 0.f, 0.f, 0.f};
  #pragma unroll
  for (int f = 0; f < 8; ++f)
    #pragma unroll
    for (int j = 0; j < 4; ++j) acc[f][j] = vzero;

  stage(0);

  #pragma unroll 1
  for (int t = 0; t < NT; ++t) {
    asm volatile("s_waitcnt vmcnt(0)" ::: "memory");   // tile t fully in LDS
    __builtin_amdgcn_s_barrier();
    asm volatile("" ::: "memory");

    short8 af[8][2], bf[4][2];

    // ---- half 0: logical granules kk*4+g0, kk in {0,1} ----
    #pragma unroll
    for (int j = 0; j < 4; ++j) {
      const int row = wc + j * 16 + l15;
      #pragma unroll
      for (int kk = 0; kk < 2; ++kk)
        bf[j][kk] = *reinterpret_cast<const short8*>(lds + 32768 + row * 128 + ((kk * 4 + g0) ^ l15) * 8);
    }
    #pragma unroll
    for (int f = 0; f < 8; ++f) {
      const int row = wr + f * 16 + l15;
      #pragma unroll
      for (int kk = 0; kk < 2; ++kk)
        af[f][kk] = *reinterpret_cast<const short8*>(lds + row * 128 + ((kk * 4 + g0) ^ l15) * 8);
    }
    asm volatile("s_waitcnt lgkmcnt(0)" ::: "memory");
    __builtin_amdgcn_sched_barrier(0);
    __builtin_amdgcn_s_setprio(1);
    #pragma unroll
    for (int f = 0; f < 8; ++f)
      #pragma unroll
      for (int j = 0; j < 4; ++j)
        #pragma unroll
        for (int kk = 0; kk < 2; ++kk)
          MFMAH(acc[f][j], af[f][kk], bf[j][kk]);
    __builtin_amdgcn_s_setprio(0);
    __builtin_amdgcn_sched_barrier(0);     // cap live ranges: half-1 reads stay below

    // ---- half 1: logical granules (kk+2)*4+g0, kk in {0,1} ----
    #pragma unroll
    for (int j = 0; j < 4; ++j) {
      const int row = wc + j * 16 + l15;
      #pragma unroll
      for (int kk = 0; kk < 2; ++kk)
        bf[j][kk] = *reinterpret_cast<const short8*>(lds + 32768 + row * 128 + (((kk + 2) * 4 + g0) ^ l15) * 8);
    }
    #pragma unroll
    for (int f = 0; f < 8; ++f) {
      const int row = wr + f * 16 + l15;
      #pragma unroll
      for (int kk = 0; kk < 2; ++kk)
        af[f][kk] = *reinterpret_cast<const short8*>(lds + row * 128 + (((kk + 2) * 4 + g0) ^ l15) * 8);
    }
    asm volatile("s_waitcnt lgkmcnt(0)" ::: "memory");
    __builtin_amdgcn_sched_barrier(0);
    __builtin_amdgcn_s_barrier();          // ALL reads of tile t retired -> buffer free

    if (t + 1 < NT) stage(t + 1);          // restage into same buffer, under MFMA

    __builtin_amdgcn_s_setprio(1);
    #pragma unroll
    for (int f = 0; f < 8; ++f)
      #pragma unroll
      for (int j = 0; j < 4; ++j)
        #pragma unroll
        for (int kk = 0; kk < 2; ++kk)
          MFMAH(acc[f][j], af[f][kk], bf[j][kk]);
    __builtin_amdgcn_s_setprio(0);
  }

  // epilogue: C/D layout col=lane&15, row=(lane>>4)*4+q (m89/m91 verified)
  const int lr = (lane >> 4) * 4;
  const int lc = lane & 15;
  #pragma unroll
  for (int f = 0; f < 8; ++f)
    #pragma unroll
    for (int j = 0; j < 4; ++j)
      #pragma unroll
      for (int q = 0; q < 4; ++q) {
        int rr = m0 + wr + f * 16 + lr + q;
        int cc = n0 + wc + j * 16 + lc;
        float v = acc[f][j][q];
        if constexpr (MODE == 2) {
          outH[(size_t)rr * 1024 + cc] = f2hu(v);
        } else {
          outF[((size_t)rr * 16 + bb) * 1024 + cc] = v;
        }
      }
}

// ---------- FUSED K2+softmax: 64x1024 tile (full S row), BK=64, NT=16 ----------
// (unchanged from r11/r12 — verified passing)
__global__ void __launch_bounds__(512, 2)
gemmF(const unsigned short* __restrict__ Hh, const unsigned short* __restrict__ Cg,
      float* __restrict__ alignOut, unsigned short* __restrict__ pOut) {
  constexpr int NT = 16;
  __shared__ __align__(16) unsigned short lds[2 * 4096 + 65536];  // A dbuf + B

  const int hw = blockIdx.x;                 // 256 blocks
  const int L  = (hw & 7) * 32 + (hw >> 3);  // XCD-chunked
  const int bb = L >> 4;                     // 16 batches
  const int m0 = (L & 15) * 64;              // 16 M-blocks of 64 rows

  const int tid  = threadIdx.x;
  const int lane = tid & 63;
  const int w    = tid >> 6;          // 8 waves: 1(M) x 8(N)
  const int l15  = lane & 15;
  const int g0   = lane >> 4;

  const int srow = tid >> 3;          // 0..63
  const int sg   = tid & 7;
  const int rs   = srow & 7;
  const unsigned short* spA = Hh + (size_t)bb * (Tdim * Ddim) + (size_t)(m0 + srow) * 1024 + ((sg ^ rs) * 8);
  const unsigned short* spB = Cg + (size_t)bb * (Sdim * Ddim) + (size_t)srow * 1024 + ((sg ^ rs) * 8);

  unsigned short* const ldsB = lds + 8192;

  auto stageA = [&](int buf, int kt) {       // 1 instr/thread (8KB tile)
    GLOADLDS(spA + kt * 64, lds + buf * 4096 + tid * 8);
  };
  auto stageB = [&](int kt) {                // 16 instr/thread (128KB)
    #pragma unroll
    for (int i = 0; i < 16; ++i)
      GLOADLDS(spB + (size_t)i * (64 * 1024) + kt * 64, ldsB + i * 4096 + tid * 8);
  };

  f32x4 acc[4][8];
  const f32x4 vzero = {0.f, 0.f, 0.f, 0.f};
  #pragma unroll
  for (int f = 0; f < 4; ++f)
    #pragma unroll
    for (int j = 0; j < 8; ++j) acc[f][j] = vzero;

  stageA(0, 0);
  stageB(0);
  stageA(1, 1);
  asm volatile("s_waitcnt vmcnt(1)" ::: "memory");
  __builtin_amdgcn_s_barrier();

  #pragma unroll 1
  for (int t = 0; t < NT; ++t) {
    const unsigned short* tA = lds + (t & 1) * 4096;

    short8 bf[8][2];
    #pragma unroll
    for (int j = 0; j < 8; ++j) {
      const int row = w * 128 + j * 16 + l15;
      #pragma unroll
      for (int kk = 0; kk < 2; ++kk)
        bf[j][kk] = *reinterpret_cast<const short8*>(ldsB + row * 64 + ((kk * 4 + g0) ^ (row & 7)) * 8);
    }
    short8 af[4][2];
    #pragma unroll
    for (int f = 0; f < 4; ++f) {
      const int row = f * 16 + l15;
      #pragma unroll
      for (int kk = 0; kk < 2; ++kk)
        af[f][kk] = *reinterpret_cast<const short8*>(tA + row * 64 + ((kk * 4 + g0) ^ (row & 7)) * 8);
    }
    asm volatile("s_waitcnt lgkmcnt(0)" ::: "memory");
    __builtin_amdgcn_sched_barrier(0);
    __builtin_amdgcn_s_barrier();          // all LDS reads retired -> buffers free

    if (t + 1 < NT) stageB(t + 1);         // restage B under MFMA phase
    if (t + 2 < NT) stageA(t & 1, t + 2);

    __builtin_amdgcn_s_setprio(1);
    #pragma unroll
    for (int f = 0; f < 4; ++f)
      #pragma unroll
      for (int j = 0; j < 8; ++j)
        #pragma unroll
        for (int kk = 0; kk < 2; ++kk)
          MFMAH(acc[f][j], af[f][kk], bf[j][kk]);
    __builtin_amdgcn_s_setprio(0);

    if (t + 1 < NT) {
      if (t + 2 < NT) asm volatile("s_waitcnt vmcnt(1)" ::: "memory");
      else            asm volatile("s_waitcnt vmcnt(0)" ::: "memory");
    }
    __builtin_amdgcn_s_barrier();
  }

  // ---- fused row softmax over full S=1024 ----
  float* red = (float*)lds;                 // reuse A region: [64][8] f32
  const int lr = (lane >> 4) * 4;

  float rmax[4][4];
  #pragma unroll
  for (int f = 0; f < 4; ++f)
    #pragma unroll
    for (int q = 0; q < 4; ++q) {
      float m = acc[f][0][q];
      #pragma unroll
      for (int j = 1; j < 8; ++j) m = fmaxf(m, acc[f][j][q]);
      #pragma unroll
      for (int o = 1; o < 16; o <<= 1) m = fmaxf(m, __shfl_xor(m, o));
      rmax[f][q] = m;
    }
  if (l15 == 0) {
    #pragma unroll
    for (int f = 0; f < 4; ++f)
      #pragma unroll
      for (int q = 0; q < 4; ++q) red[(f * 16 + lr + q) * 8 + w] = rmax[f][q];
  }
  __syncthreads();
  #pragma unroll
  for (int f = 0; f < 4; ++f)
    #pragma unroll
    for (int q = 0; q < 4; ++q) {
      const float* rr = red + (f * 16 + lr + q) * 8;
      float m = rr[0];
      #pragma unroll
      for (int k = 1; k < 8; ++k) m = fmaxf(m, rr[k]);
      rmax[f][q] = m;
    }
  __syncthreads();

  float rsum[4][4];
  #pragma unroll
  for (int f = 0; f < 4; ++f)
    #pragma unroll
    for (int q = 0; q < 4; ++q) {
      float s = 0.f;
      #pragma unroll
      for (int j = 0; j < 8; ++j) {
        float e = __expf(acc[f][j][q] - rmax[f][q]);
        acc[f][j][q] = e;
        s += e;
      }
      #pragma unroll
      for (int o = 1; o < 16; o <<= 1) s += __shfl_xor(s, o);
      rsum[f][q] = s;
    }
  if (l15 == 0) {
    #pragma unroll
    for (int f = 0; f < 4; ++f)
      #pragma unroll
      for (int q = 0; q < 4; ++q) red[(f * 16 + lr + q) * 8 + w] = rsum[f][q];
  }
  __syncthreads();
  #pragma unroll
  for (int f = 0; f < 4; ++f)
    #pragma unroll
    for (int q = 0; q < 4; ++q) {
      const float* rr = red + (f * 16 + lr + q) * 8;
      float s = ((rr[0] + rr[1]) + (rr[2] + rr[3])) + ((rr[4] + rr[5]) + (rr[6] + rr[7]));
      rsum[f][q] = 1.0f / s;
    }

  #pragma unroll
  for (int f = 0; f < 4; ++f)
    #pragma unroll
    for (int q = 0; q < 4; ++q) {
      const int row = m0 + f * 16 + lr + q;
      float inv = rsum[f][q];
      #pragma unroll
      for (int j = 0; j < 8; ++j) {
        const int cc = w * 128 + j * 16 + l15;
        float v = acc[f][j][q] * inv;
        alignOut[((size_t)row * 16 + bb) * 1024 + cc] = v;
        pOut[((size_t)bb * 1024 + row) * 1024 + cc] = f2hu(v);
      }
    }
}

extern "C" void kernel_launch(void* const* d_in, const int* in_sizes, int n_in,
                              void* d_out, int out_size, void* d_ws, size_t ws_size,
                              hipStream_t stream) {
  const float* input = (const float*)d_in[0];  // [B,T,D]
  const float* ctx   = (const float*)d_in[1];  // [B,S,D]
  const float* Wt    = (const float*)d_in[2];  // [D,D]
  float* attn_out  = (float*)d_out;                               // [T,B,D]
  float* align_out = attn_out + (size_t)Tdim * Bdim * Ddim;       // [T,B,S]

  const size_t NE = (size_t)Bdim * Tdim * Ddim;  // 16M elems
  unsigned short* x16  = (unsigned short*)d_ws;  // 32MB, reused as ctx16 after K1
  unsigned short* Wh   = x16 + NE;               // 2MB
  unsigned short* hh   = Wh + (size_t)Ddim * Ddim;  // 32MB, overwritten by p in gemmF
  unsigned short* ctxT = hh + NE;                // 32MB
  unsigned short* ctx16 = x16;
  unsigned short* p     = hh;

  conv_kernel<<<2048, 256, 0, stream>>>(input, x16, (int)(NE / 4));
  conv_kernel<<<512, 256, 0, stream>>>(Wt, Wh, (int)((size_t)Ddim * Ddim / 4));
  // K1: h = x @ W^T, plain fp16 -> hh
  gemmP<2><<<256, 512, 0, stream>>>(x16, Wh, 0, 0, 8, hh, nullptr);
  // ctx16 [B,S,D] + ctxT [B,D,S] fp16 (ctx16 into dead x region)
  ctxprep_kernel<<<dim3(16, 16, Bdim), 256, 0, stream>>>(ctx, ctx16, ctxT);
  // K2 fused: align = softmax(h @ ctx^T) -> align_out f32 [T,B,S], p fp16
  gemmF<<<256, 512, 0, stream>>>(hh, ctx16, align_out, p);
  // K4: attn = p @ ctx, plain fp16 -> f32 [T,B,D]
  gemmP<1><<<256, 512, 0, stream>>>(p, ctxT, (size_t)Tdim * Sdim,
                                    (size_t)Ddim * Sdim, 4, nullptr, attn_out);
}